// Round 2
// baseline (8114.453 us; speedup 1.0000x reference)
//
#include <hip/hip_runtime.h>
#include <hip/hip_bf16.h>
#include <math.h>

#define BATCH 2
#define NTOK 1024
#define DMODEL 512
#define NHEAD 8
#define DH 64
#define NLAYER 4
#define MMODES 256
#define DFFN 2048

typedef __hip_bfloat16 bf16;

__device__ __forceinline__ float b2f(bf16 x) { return __bfloat162float(x); }
// dtype-flexible load: f32 != 0 -> buffer is float32, else bf16
__device__ __forceinline__ float ldx(const void* p, size_t i, int f32) {
    return f32 ? ((const float*)p)[i] : b2f(((const bf16*)p)[i]);
}

// ---- dtype probe: look at low-half u16 of the first 768 "elements" of a
// Gaussian weight buffer. true-bf16: even u16s are real small values.
// fp32: even u16s are random mantissa bits (~46% exponent>=137) or all zero
// (if data was bf16-rounded then stored as fp32).
__global__ __launch_bounds__(256) void detect_kernel(const void* __restrict__ probe,
                                                     int* __restrict__ flag) {
    const unsigned short* u = (const unsigned short*)probe;
    int big = 0, zer = 0;
    for (int t = threadIdx.x; t < 768; t += 256) {
        unsigned short w = u[2 * t];
        int e = (w >> 7) & 0xFF;
        if (e >= 137) big++;          // |bf16| >= 1024, or inf/nan
        if (w == 0) zer++;
    }
    __shared__ int sb, sz;
    if (threadIdx.x == 0) { sb = 0; sz = 0; }
    __syncthreads();
    atomicAdd(&sb, big);
    atomicAdd(&sz, zer);
    __syncthreads();
    if (threadIdx.x == 0) flag[0] = (sb >= 64 || sz >= 700) ? 1 : 0;
}

// ---- elementwise convert input -> fp32 ----
__global__ __launch_bounds__(256) void cvt_kernel(const void* __restrict__ in,
                                                  float* __restrict__ out, int n,
                                                  const int* __restrict__ fl) {
    int f = fl[0];
    int i = blockIdx.x * 256 + threadIdx.x;
    if (i < n) out[i] = ldx(in, i, f);
}

// ---- Fourier features ----
__global__ __launch_bounds__(256) void feats_kernel(const void* __restrict__ coords,
                                                    const void* __restrict__ modes,
                                                    float* __restrict__ ff,
                                                    const int* __restrict__ fl) {
    int f = fl[0];
    int row = blockIdx.x;   // 0..2047
    int m = threadIdx.x;    // 0..255
    float cx = ldx(coords, (size_t)row * 3 + 0, f);
    float cy = ldx(coords, (size_t)row * 3 + 1, f);
    float cz = ldx(coords, (size_t)row * 3 + 2, f);
    float ph = cx * ldx(modes, (size_t)m * 3 + 0, f)
             + cy * ldx(modes, (size_t)m * 3 + 1, f)
             + cz * ldx(modes, (size_t)m * 3 + 2, f);
    ff[(size_t)row * (2 * MMODES) + m] = cosf(ph);
    ff[(size_t)row * (2 * MMODES) + MMODES + m] = sinf(ph);
}

// ---- distance statistics: per-(b,i) row partial sum & sumsq ----
__global__ __launch_bounds__(256) void dstat_kernel(const void* __restrict__ coords,
                                                    float* __restrict__ part,
                                                    const int* __restrict__ fl) {
    int f = fl[0];
    int b = blockIdx.x >> 10, i = blockIdx.x & 1023;
    size_t cb = (size_t)b * NTOK * 3;
    float xi = ldx(coords, cb + (size_t)i * 3 + 0, f);
    float yi = ldx(coords, cb + (size_t)i * 3 + 1, f);
    float zi = ldx(coords, cb + (size_t)i * 3 + 2, f);
    float ls = 0.f, ls2 = 0.f;
    for (int j = threadIdx.x; j < NTOK; j += 256) {
        float dx = xi - (ldx(coords, cb + (size_t)j * 3 + 0, f) + 1e-5f);
        float dy = yi - (ldx(coords, cb + (size_t)j * 3 + 1, f) + 1e-5f);
        float dz = zi - (ldx(coords, cb + (size_t)j * 3 + 2, f) + 1e-5f);
        float d = sqrtf(dx * dx + dy * dy + dz * dz);
        ls += d;
        ls2 += d * d;
    }
    for (int off = 32; off; off >>= 1) {
        ls += __shfl_down(ls, off);
        ls2 += __shfl_down(ls2, off);
    }
    __shared__ float rs[4], rs2[4];
    int wid = threadIdx.x >> 6;
    if ((threadIdx.x & 63) == 0) { rs[wid] = ls; rs2[wid] = ls2; }
    __syncthreads();
    if (threadIdx.x == 0) {
        part[blockIdx.x] = rs[0] + rs[1] + rs[2] + rs[3];
        part[2048 + blockIdx.x] = rs2[0] + rs2[1] + rs2[2] + rs2[3];
    }
}

// ---- reduce partials -> inv std (ddof=1), one block per batch ----
__global__ __launch_bounds__(256) void dreduce_kernel(const float* __restrict__ part,
                                                      float* __restrict__ inv_std) {
    int b = blockIdx.x;
    double s = 0.0, s2 = 0.0;
    for (int t = threadIdx.x; t < NTOK; t += 256) {
        s += (double)part[b * NTOK + t];
        s2 += (double)part[2048 + b * NTOK + t];
    }
    for (int off = 32; off; off >>= 1) {
        s += __shfl_down(s, off);
        s2 += __shfl_down(s2, off);
    }
    __shared__ double ds[4], ds2[4];
    int wid = threadIdx.x >> 6;
    if ((threadIdx.x & 63) == 0) { ds[wid] = s; ds2[wid] = s2; }
    __syncthreads();
    if (threadIdx.x == 0) {
        double S = ds[0] + ds[1] + ds[2] + ds[3];
        double S2 = ds2[0] + ds2[1] + ds2[2] + ds2[3];
        double n = (double)NTOK * (double)NTOK;
        double mean = S / n;
        double var = (S2 - n * mean * mean) / (n - 1.0);
        inv_std[b] = (float)(1.0 / sqrt(var));
    }
}

// ---- LayerNorm (row of 512) -> fp32 ws ----
__global__ __launch_bounds__(256) void ln_kernel(const float* __restrict__ x,
                                                 const void* __restrict__ g, size_t gOff,
                                                 const void* __restrict__ b, size_t bOff,
                                                 float* __restrict__ y,
                                                 const int* __restrict__ fl) {
    int f = fl[0];
    int row = blockIdx.x;
    const float* xr = x + (size_t)row * DMODEL;
    int tid = threadIdx.x;
    float v0 = xr[tid], v1 = xr[tid + 256];
    float s = v0 + v1, s2 = v0 * v0 + v1 * v1;
    for (int off = 32; off; off >>= 1) {
        s += __shfl_down(s, off);
        s2 += __shfl_down(s2, off);
    }
    __shared__ float ls[4], ls2[4];
    int wid = tid >> 6;
    if ((tid & 63) == 0) { ls[wid] = s; ls2[wid] = s2; }
    __syncthreads();
    s = ls[0] + ls[1] + ls[2] + ls[3];
    s2 = ls2[0] + ls2[1] + ls2[2] + ls2[3];
    float mean = s * (1.0f / DMODEL);
    float var = s2 * (1.0f / DMODEL) - mean * mean;
    float r = rsqrtf(var + 1e-5f);
    y[(size_t)row * DMODEL + tid] =
        (v0 - mean) * r * ldx(g, gOff + tid, f) + ldx(b, bOff + tid, f);
    y[(size_t)row * DMODEL + tid + 256] =
        (v1 - mean) * r * ldx(g, gOff + tid + 256, f) + ldx(b, bOff + tid + 256, f);
}

// ---- final LayerNorm -> d_out (dtype-switched store) ----
__global__ __launch_bounds__(256) void ln_out_kernel(const float* __restrict__ x,
                                                     const void* __restrict__ g,
                                                     const void* __restrict__ b,
                                                     void* __restrict__ out,
                                                     const int* __restrict__ fl) {
    int f = fl[0];
    int row = blockIdx.x;
    const float* xr = x + (size_t)row * DMODEL;
    int tid = threadIdx.x;
    float v0 = xr[tid], v1 = xr[tid + 256];
    float s = v0 + v1, s2 = v0 * v0 + v1 * v1;
    for (int off = 32; off; off >>= 1) {
        s += __shfl_down(s, off);
        s2 += __shfl_down(s2, off);
    }
    __shared__ float ls[4], ls2[4];
    int wid = tid >> 6;
    if ((tid & 63) == 0) { ls[wid] = s; ls2[wid] = s2; }
    __syncthreads();
    s = ls[0] + ls[1] + ls[2] + ls[3];
    s2 = ls2[0] + ls2[1] + ls2[2] + ls2[3];
    float mean = s * (1.0f / DMODEL);
    float var = s2 * (1.0f / DMODEL) - mean * mean;
    float r = rsqrtf(var + 1e-5f);
    float o0 = (v0 - mean) * r * ldx(g, tid, f) + ldx(b, tid, f);
    float o1 = (v1 - mean) * r * ldx(g, tid + 256, f) + ldx(b, tid + 256, f);
    size_t i0 = (size_t)row * DMODEL + tid;
    if (f) {
        ((float*)out)[i0] = o0;
        ((float*)out)[i0 + 256] = o1;
    } else {
        ((bf16*)out)[i0] = __float2bfloat16(o0);
        ((bf16*)out)[i0 + 256] = __float2bfloat16(o1);
    }
}

// ---- generic tiled GEMM: C = [res +] act(A@W + bias) ----
#define BM 64
#define BN 64
#define BK 16
template <int ACT, bool HAS_RES>
__global__ __launch_bounds__(256) void gemm_kernel(const float* __restrict__ A,
                                                   const void* __restrict__ W, size_t wOff,
                                                   const void* __restrict__ bias, size_t bOff,
                                                   const float* __restrict__ res,
                                                   float* __restrict__ C,
                                                   int M, int N, int K,
                                                   const int* __restrict__ fl) {
    const int f = fl[0];
    __shared__ float As[BK][BM + 1];
    __shared__ float Ws[BK][BN + 1];
    int n0 = blockIdx.x * BN;
    int m0 = blockIdx.y * BM;
    int tid = threadIdx.x;
    int tx = tid & 15, ty = tid >> 4;
    float acc[4][4] = {};
    for (int k0 = 0; k0 < K; k0 += BK) {
#pragma unroll
        for (int i = 0; i < 4; i++) {
            int idx = tid + i * 256;
            int r = idx >> 4, c = idx & 15;
            As[c][r] = A[(size_t)(m0 + r) * K + k0 + c];
        }
#pragma unroll
        for (int i = 0; i < 4; i++) {
            int idx = tid + i * 256;
            int r = idx >> 6, c = idx & 63;
            Ws[r][c] = ldx(W, wOff + (size_t)(k0 + r) * N + n0 + c, f);
        }
        __syncthreads();
#pragma unroll
        for (int kk = 0; kk < BK; kk++) {
            float a[4], bb[4];
#pragma unroll
            for (int i = 0; i < 4; i++) a[i] = As[kk][ty * 4 + i];
#pragma unroll
            for (int j = 0; j < 4; j++) bb[j] = Ws[kk][tx * 4 + j];
#pragma unroll
            for (int i = 0; i < 4; i++)
#pragma unroll
                for (int j = 0; j < 4; j++) acc[i][j] += a[i] * bb[j];
        }
        __syncthreads();
    }
#pragma unroll
    for (int i = 0; i < 4; i++) {
        int m = m0 + ty * 4 + i;
#pragma unroll
        for (int j = 0; j < 4; j++) {
            int n = n0 + tx * 4 + j;
            float v = acc[i][j] + ldx(bias, bOff + n, f);
            if (ACT == 1) v = 0.5f * v * (1.0f + erff(v * 0.70710678118654752f));
            if (HAS_RES) v += res[(size_t)m * N + n];
            C[(size_t)m * N + n] = v;
        }
    }
}

// ---- attention: one block per (b,h,i); distances recomputed from LDS coords ----
__global__ __launch_bounds__(256) void attn_kernel(const float* __restrict__ q,
                                                   const float* __restrict__ k,
                                                   const float* __restrict__ v,
                                                   const void* __restrict__ coords,
                                                   const float* __restrict__ inv_std,
                                                   const void* __restrict__ temp, size_t tOff,
                                                   float* __restrict__ o,
                                                   const int* __restrict__ fl) {
    const int f = fl[0];
    const int i = blockIdx.x, h = blockIdx.y, b = blockIdx.z;
    const int tid = threadIdx.x;
    __shared__ float s_cx[NTOK], s_cy[NTOK], s_cz[NTOK];
    __shared__ __align__(16) float s_q[DH];
    __shared__ float s_sc[NTOK];
    __shared__ float red[8];
    __shared__ float s_o[4][DH];
    size_t cb = (size_t)b * NTOK * 3;
    for (int t = tid; t < NTOK; t += 256) {
        s_cx[t] = ldx(coords, cb + (size_t)t * 3 + 0, f);
        s_cy[t] = ldx(coords, cb + (size_t)t * 3 + 1, f);
        s_cz[t] = ldx(coords, cb + (size_t)t * 3 + 2, f);
    }
    const float* qrow = q + ((size_t)(b * NTOK + i)) * DMODEL + h * DH;
    if (tid < DH) s_q[tid] = qrow[tid];
    __syncthreads();
    float t0 = ldx(temp, tOff + h, f);
    float sp = fmaxf(t0, 0.f) + log1pf(expf(-fabsf(t0)));  // stable softplus
    float istd = inv_std[b];
    const float scale = 0.125f;  // 1/sqrt(64)
    float cxi = s_cx[i], cyi = s_cy[i], czi = s_cz[i];
    const float* kb = k + (size_t)b * NTOK * DMODEL + h * DH;
    const float4* q4 = (const float4*)s_q;
    for (int j = tid; j < NTOK; j += 256) {
        const float4* k4 = (const float4*)(kb + (size_t)j * DMODEL);
        float acc = 0.f;
#pragma unroll
        for (int tt = 0; tt < 16; tt++) {
            float4 kv = k4[tt];
            float4 qv = q4[tt];
            acc += qv.x * kv.x + qv.y * kv.y + qv.z * kv.z + qv.w * kv.w;
        }
        float dx = cxi - (s_cx[j] + 1e-5f);
        float dy = cyi - (s_cy[j] + 1e-5f);
        float dz = czi - (s_cz[j] + 1e-5f);
        float d = sqrtf(dx * dx + dy * dy + dz * dz);
        s_sc[j] = acc * scale - sp * istd * d;
    }
    __syncthreads();
    float m = -1e30f;
    for (int j = tid; j < NTOK; j += 256) m = fmaxf(m, s_sc[j]);
    for (int off = 32; off; off >>= 1) m = fmaxf(m, __shfl_down(m, off));
    if ((tid & 63) == 0) red[tid >> 6] = m;
    __syncthreads();
    m = fmaxf(fmaxf(red[0], red[1]), fmaxf(red[2], red[3]));
    float zs = 0.f;
    for (int j = tid; j < NTOK; j += 256) {
        float p = expf(s_sc[j] - m);
        s_sc[j] = p;
        zs += p;
    }
    for (int off = 32; off; off >>= 1) zs += __shfl_down(zs, off);
    if ((tid & 63) == 0) red[4 + (tid >> 6)] = zs;
    __syncthreads();
    float rz = 1.0f / (red[4] + red[5] + red[6] + red[7]);
    int dd = tid & 63, g = tid >> 6;
    const float* vb = v + (size_t)b * NTOK * DMODEL + h * DH + dd;
    float acc = 0.f;
    for (int j = g; j < NTOK; j += 4) acc += s_sc[j] * vb[(size_t)j * DMODEL];
    s_o[g][dd] = acc;
    __syncthreads();
    if (tid < DH) {
        float r = (s_o[0][tid] + s_o[1][tid] + s_o[2][tid] + s_o[3][tid]) * rz;
        o[((size_t)(b * NTOK + i)) * DMODEL + h * DH + tid] = r;
    }
}

extern "C" void kernel_launch(void* const* d_in, const int* in_sizes, int n_in,
                              void* d_out, int out_size, void* d_ws, size_t ws_size,
                              hipStream_t stream) {
    const void* phi    = d_in[0];
    const void* coords = d_in[1];
    const void* modes  = d_in[2];
    const void* We     = d_in[3];
    const void* be     = d_in[4];
    const void* wq     = d_in[5];
    const void* bq     = d_in[6];
    const void* wk     = d_in[7];
    const void* bk     = d_in[8];
    const void* wv     = d_in[9];
    const void* bv     = d_in[10];
    const void* wo     = d_in[11];
    const void* bo     = d_in[12];
    const void* temp   = d_in[13];
    const void* ln1g   = d_in[14];
    const void* ln1b   = d_in[15];
    const void* ln2g   = d_in[16];
    const void* ln2b   = d_in[17];
    const void* w1     = d_in[18];
    const void* b1     = d_in[19];
    const void* w2     = d_in[20];
    const void* b2     = d_in[21];
    const void* fng    = d_in[22];
    const void* fnb    = d_in[23];

    const int R = BATCH * NTOK;  // 2048 rows
    char* ws = (char*)d_ws;
    const size_t MB = 1u << 20;
    float* xf   = (float*)(ws + 0 * MB);   // [R, D]   4 MB (persistent)
    float* yf   = (float*)(ws + 4 * MB);   // [R, D]   4 MB
    float* pool = (float*)(ws + 8 * MB);   // 16 MB: ff | q,k,v,o | FFN hidden
    float* ff = pool;                      // [R, 2M]  4 MB  (encode only)
    float* qf = pool;                      // [R, D]
    float* kf = pool + 1 * MB;             // [R, D]   (float* arith: 4 MB steps)
    float* vf = pool + 2 * MB;
    float* of = pool + 3 * MB;
    float* hf = pool;                      // [R, DFF] 16 MB (FFN only)
    float* part    = (float*)(ws + 24 * MB);           // 4096 floats
    float* inv_std = (float*)(ws + 24 * MB + 32768);   // 2 floats
    int*   flag    = (int*)(ws + 24 * MB + 65536);     // 1 int

    // dtype probe on wq (1M Gaussian elements — safe to over-read 3 KB)
    detect_kernel<<<1, 256, 0, stream>>>(wq, flag);

    // encode: x = phi + feats @ We + be
    cvt_kernel<<<(R * DMODEL + 255) / 256, 256, 0, stream>>>(phi, xf, R * DMODEL, flag);
    feats_kernel<<<R, 256, 0, stream>>>(coords, modes, ff, flag);
    gemm_kernel<0, true><<<dim3(DMODEL / BN, R / BM), 256, 0, stream>>>(
        ff, We, 0, be, 0, xf, xf, R, DMODEL, 2 * MMODES, flag);

    // distance statistics -> per-batch inv std (ddof=1)
    dstat_kernel<<<R, 256, 0, stream>>>(coords, part, flag);
    dreduce_kernel<<<BATCH, 256, 0, stream>>>(part, inv_std);

    for (int l = 0; l < NLAYER; l++) {
        const size_t wOff = (size_t)l * DMODEL * DMODEL;
        const size_t fOff = (size_t)l * DMODEL * DFFN;
        ln_kernel<<<R, 256, 0, stream>>>(xf, ln1g, (size_t)l * DMODEL, ln1b,
                                         (size_t)l * DMODEL, yf, flag);
        gemm_kernel<0, false><<<dim3(DMODEL / BN, R / BM), 256, 0, stream>>>(
            yf, wq, wOff, bq, (size_t)l * DMODEL, nullptr, qf, R, DMODEL, DMODEL, flag);
        gemm_kernel<0, false><<<dim3(DMODEL / BN, R / BM), 256, 0, stream>>>(
            yf, wk, wOff, bk, (size_t)l * DMODEL, nullptr, kf, R, DMODEL, DMODEL, flag);
        gemm_kernel<0, false><<<dim3(DMODEL / BN, R / BM), 256, 0, stream>>>(
            yf, wv, wOff, bv, (size_t)l * DMODEL, nullptr, vf, R, DMODEL, DMODEL, flag);
        attn_kernel<<<dim3(NTOK, NHEAD, BATCH), 256, 0, stream>>>(
            qf, kf, vf, coords, inv_std, temp, (size_t)l * NHEAD, of, flag);
        gemm_kernel<0, true><<<dim3(DMODEL / BN, R / BM), 256, 0, stream>>>(
            of, wo, wOff, bo, (size_t)l * DMODEL, xf, xf, R, DMODEL, DMODEL, flag);
        ln_kernel<<<R, 256, 0, stream>>>(xf, ln2g, (size_t)l * DMODEL, ln2b,
                                         (size_t)l * DMODEL, yf, flag);
        gemm_kernel<1, false><<<dim3(DFFN / BN, R / BM), 256, 0, stream>>>(
            yf, w1, fOff, b1, (size_t)l * DFFN, nullptr, hf, R, DFFN, DMODEL, flag);
        gemm_kernel<0, true><<<dim3(DMODEL / BN, R / BM), 256, 0, stream>>>(
            hf, w2, fOff, b2, (size_t)l * DMODEL, xf, xf, R, DMODEL, DFFN, flag);
    }
    ln_out_kernel<<<R, 256, 0, stream>>>(xf, fng, fnb, d_out, flag);
}

// Round 3
// 1040.996 us; speedup vs baseline: 7.7949x; 7.7949x over previous
//
#include <hip/hip_runtime.h>
#include <hip/hip_bf16.h>
#include <math.h>

#define BATCH 2
#define NTOK 1024
#define DMODEL 512
#define NHEAD 8
#define DH 64
#define NLAYER 4
#define MMODES 256
#define DFFN 2048

typedef unsigned short u16;
typedef __attribute__((ext_vector_type(4))) float f4;
typedef __attribute__((ext_vector_type(8))) short b8;

__device__ __forceinline__ float bf2f(u16 u) { return __uint_as_float(((unsigned)u) << 16); }
__device__ __forceinline__ u16 f2b(float x) {
    unsigned u = __float_as_uint(x);
    return (u16)((u + 0x7FFF + ((u >> 16) & 1)) >> 16);
}
// dtype-flexible load from raw input buffers: f32!=0 -> float32, else bf16
__device__ __forceinline__ float ldx(const void* p, size_t i, int f32) {
    return f32 ? ((const float*)p)[i] : bf2f(((const u16*)p)[i]);
}

// ================= dtype probe (same as round 2, verified working) =================
__global__ __launch_bounds__(256) void detect_kernel(const void* __restrict__ probe,
                                                     int* __restrict__ flag) {
    const u16* u = (const u16*)probe;
    int big = 0, zer = 0;
    for (int t = threadIdx.x; t < 768; t += 256) {
        u16 w = u[2 * t];
        int e = (w >> 7) & 0xFF;
        if (e >= 137) big++;
        if (w == 0) zer++;
    }
    __shared__ int sb, sz;
    if (threadIdx.x == 0) { sb = 0; sz = 0; }
    __syncthreads();
    atomicAdd(&sb, big);
    atomicAdd(&sz, zer);
    __syncthreads();
    if (threadIdx.x == 0) flag[0] = (sb >= 64 || sz >= 700) ? 1 : 0;
}

// ================= convert phi -> xf (fp32) and coords -> cf (fp32) =================
__global__ __launch_bounds__(256) void cvt_all_kernel(const void* __restrict__ phi,
                                                      const void* __restrict__ coords,
                                                      float* __restrict__ xf,
                                                      float* __restrict__ cf,
                                                      const int* __restrict__ fl) {
    int f = fl[0];
    int i = blockIdx.x * 256 + threadIdx.x;
    if (i < BATCH * NTOK * DMODEL) xf[i] = ldx(phi, i, f);
    if (i < BATCH * NTOK * 3) cf[i] = ldx(coords, i, f);
}

// ================= pack all small params to fp32 =================
// layout (floats): be[512] | bqkv[4][1536] | bo[4][512] | b1[4][2048] | b2[4][512]
//  | temp[4][8] | ln1g[4][512] | ln1b | ln2g | ln2b | fng[512] | fnb[512] | modes[256*3]
#define OB_BE 0
#define OB_BQKV 512
#define OB_BO 6656
#define OB_B1 8704
#define OB_B2 16896
#define OB_TEMP 18944
#define OB_L1G 18976
#define OB_L1B 21024
#define OB_L2G 23072
#define OB_L2B 25120
#define OB_FNG 27168
#define OB_FNB 27680
#define OB_MODES 28192
#define OB_TOTAL 28960
__global__ __launch_bounds__(256) void pack_params(
    const void* be_, const void* bq_, const void* bk_, const void* bv_,
    const void* bo_, const void* b1_, const void* b2_, const void* temp_,
    const void* l1g_, const void* l1b_, const void* l2g_, const void* l2b_,
    const void* fng_, const void* fnb_, const void* modes_,
    float* __restrict__ out, const int* __restrict__ fl) {
    int f = fl[0];
    for (int idx = blockIdx.x * 256 + threadIdx.x; idx < OB_TOTAL; idx += gridDim.x * 256) {
        float v;
        int i = idx;
        if (i < 512) v = ldx(be_, i, f);
        else if ((i -= 512) < 6144) {
            int l = i / 1536, r = i - l * 1536;
            v = (r < 512) ? ldx(bq_, (size_t)l * 512 + r, f)
              : (r < 1024) ? ldx(bk_, (size_t)l * 512 + r - 512, f)
              : ldx(bv_, (size_t)l * 512 + r - 1024, f);
        }
        else if ((i -= 6144) < 2048) v = ldx(bo_, i, f);
        else if ((i -= 2048) < 8192) v = ldx(b1_, i, f);
        else if ((i -= 8192) < 2048) v = ldx(b2_, i, f);
        else if ((i -= 2048) < 32)   v = ldx(temp_, i, f);
        else if ((i -= 32) < 2048)   v = ldx(l1g_, i, f);
        else if ((i -= 2048) < 2048) v = ldx(l1b_, i, f);
        else if ((i -= 2048) < 2048) v = ldx(l2g_, i, f);
        else if ((i -= 2048) < 2048) v = ldx(l2b_, i, f);
        else if ((i -= 2048) < 512)  v = ldx(fng_, i, f);
        else if ((i -= 512) < 512)   v = ldx(fnb_, i, f);
        else { i -= 512; v = ldx(modes_, i, f); }
        out[idx] = v;
    }
}

// ================= weight transpose to bf16 W^T [C][R] from src [R][C] =================
// generic body shared by the three variants below
__device__ __forceinline__ void tr_body(const void* src, size_t sbase, u16* dst,
                                        size_t dbase, int R, int C, int dstRowOff, int f) {
    __shared__ float t[32][33];
    int c0 = blockIdx.x * 32, r0 = blockIdx.y * 32;
    int tx = threadIdx.x & 31, ty8 = threadIdx.x >> 5;
#pragma unroll
    for (int rr = 0; rr < 4; rr++) {
        int r = r0 + ty8 + rr * 8;
        t[ty8 + rr * 8][tx] = ldx(src, sbase + (size_t)r * C + c0 + tx, f);
    }
    __syncthreads();
#pragma unroll
    for (int rr = 0; rr < 4; rr++) {
        int c = c0 + ty8 + rr * 8;
        dst[dbase + (size_t)(dstRowOff + c) * R + r0 + tx] = f2b(t[tx][ty8 + rr * 8]);
    }
}
// qkv pack: z = l*3 + mat; dst rows [mat*512 + c] of wqkvT[l] ([1536][512])
__global__ __launch_bounds__(256) void tr_qkv(const void* wq_, const void* wk_,
                                              const void* wv_, u16* dst,
                                              const int* __restrict__ fl) {
    int z = blockIdx.z, l = z / 3, mat = z - l * 3;
    const void* s = (mat == 0) ? wq_ : (mat == 1) ? wk_ : wv_;
    tr_body(s, (size_t)l * 512 * 512, dst, (size_t)l * 1536 * 512, 512, 512, mat * 512, fl[0]);
}
// wo (z=0..3) + We (z=4): both [512][512]
__global__ __launch_bounds__(256) void tr_woWe(const void* wo_, const void* We_,
                                               u16* woT, u16* WeT,
                                               const int* __restrict__ fl) {
    int z = blockIdx.z;
    if (z < 4) tr_body(wo_, (size_t)z * 512 * 512, woT, (size_t)z * 512 * 512, 512, 512, 0, fl[0]);
    else       tr_body(We_, 0, WeT, 0, 512, 512, 0, fl[0]);
}
// generic per-layer: src [R][C] x4 -> dst [C][R] x4
__global__ __launch_bounds__(256) void tr_gen(const void* src, u16* dst, int R, int C,
                                              const int* __restrict__ fl) {
    int z = blockIdx.z;
    tr_body(src, (size_t)z * R * C, dst, (size_t)z * R * C, R, C, 0, fl[0]);
}

// ================= Fourier features -> bf16 =================
__global__ __launch_bounds__(256) void feats_kernel(const float* __restrict__ cf,
                                                    const float* __restrict__ modesF,
                                                    u16* __restrict__ ff) {
    int row = blockIdx.x, m = threadIdx.x;
    float cx = cf[row * 3 + 0], cy = cf[row * 3 + 1], cz = cf[row * 3 + 2];
    float ph = cx * modesF[m * 3 + 0] + cy * modesF[m * 3 + 1] + cz * modesF[m * 3 + 2];
    ff[(size_t)row * 512 + m] = f2b(cosf(ph));
    ff[(size_t)row * 512 + MMODES + m] = f2b(sinf(ph));
}

// ================= distance stats (ddof=1 inv-std per batch) =================
__global__ __launch_bounds__(256) void dstat_kernel(const float* __restrict__ cf,
                                                    float* __restrict__ part) {
    int b = blockIdx.x >> 10, i = blockIdx.x & 1023;
    const float* cb = cf + (size_t)b * NTOK * 3;
    float xi = cb[i * 3], yi = cb[i * 3 + 1], zi = cb[i * 3 + 2];
    float ls = 0.f, ls2 = 0.f;
    for (int j = threadIdx.x; j < NTOK; j += 256) {
        float dx = xi - (cb[j * 3] + 1e-5f);
        float dy = yi - (cb[j * 3 + 1] + 1e-5f);
        float dz = zi - (cb[j * 3 + 2] + 1e-5f);
        float d = sqrtf(dx * dx + dy * dy + dz * dz);
        ls += d; ls2 += d * d;
    }
    for (int off = 32; off; off >>= 1) {
        ls += __shfl_down(ls, off);
        ls2 += __shfl_down(ls2, off);
    }
    __shared__ float rs[4], rs2[4];
    int wid = threadIdx.x >> 6;
    if ((threadIdx.x & 63) == 0) { rs[wid] = ls; rs2[wid] = ls2; }
    __syncthreads();
    if (threadIdx.x == 0) {
        part[blockIdx.x] = rs[0] + rs[1] + rs[2] + rs[3];
        part[2048 + blockIdx.x] = rs2[0] + rs2[1] + rs2[2] + rs2[3];
    }
}
__global__ __launch_bounds__(256) void dreduce_kernel(const float* __restrict__ part,
                                                      float* __restrict__ inv_std) {
    int b = blockIdx.x;
    double s = 0.0, s2 = 0.0;
    for (int t = threadIdx.x; t < NTOK; t += 256) {
        s += (double)part[b * NTOK + t];
        s2 += (double)part[2048 + b * NTOK + t];
    }
    for (int off = 32; off; off >>= 1) {
        s += __shfl_down(s, off);
        s2 += __shfl_down(s2, off);
    }
    __shared__ double ds[4], ds2[4];
    int wid = threadIdx.x >> 6;
    if ((threadIdx.x & 63) == 0) { ds[wid] = s; ds2[wid] = s2; }
    __syncthreads();
    if (threadIdx.x == 0) {
        double S = ds[0] + ds[1] + ds[2] + ds[3];
        double S2 = ds2[0] + ds2[1] + ds2[2] + ds2[3];
        double n = (double)NTOK * (double)NTOK;
        double mean = S / n;
        double var = (S2 - n * mean * mean) / (n - 1.0);
        inv_std[b] = (float)(1.0 / sqrt(var));
    }
}

// ================= LayerNorm: fp32 in -> bf16 out =================
__global__ __launch_bounds__(256) void ln_bf_kernel(const float* __restrict__ x,
                                                    const float* __restrict__ gp,
                                                    const float* __restrict__ bp,
                                                    u16* __restrict__ y) {
    int row = blockIdx.x, tid = threadIdx.x;
    const float* xr = x + (size_t)row * DMODEL;
    float v0 = xr[tid], v1 = xr[tid + 256];
    float s = v0 + v1, s2 = v0 * v0 + v1 * v1;
    for (int off = 32; off; off >>= 1) {
        s += __shfl_down(s, off);
        s2 += __shfl_down(s2, off);
    }
    __shared__ float ls[4], ls2[4];
    int wid = tid >> 6;
    if ((tid & 63) == 0) { ls[wid] = s; ls2[wid] = s2; }
    __syncthreads();
    s = ls[0] + ls[1] + ls[2] + ls[3];
    s2 = ls2[0] + ls2[1] + ls2[2] + ls2[3];
    float mean = s * (1.0f / DMODEL);
    float var = s2 * (1.0f / DMODEL) - mean * mean;
    float r = rsqrtf(var + 1e-5f);
    y[(size_t)row * DMODEL + tid] = f2b((v0 - mean) * r * gp[tid] + bp[tid]);
    y[(size_t)row * DMODEL + tid + 256] = f2b((v1 - mean) * r * gp[tid + 256] + bp[tid + 256]);
}
// final LN -> d_out (dtype-switched store)
__global__ __launch_bounds__(256) void ln_out_kernel(const float* __restrict__ x,
                                                     const float* __restrict__ gp,
                                                     const float* __restrict__ bp,
                                                     void* __restrict__ out,
                                                     const int* __restrict__ fl) {
    int f = fl[0];
    int row = blockIdx.x, tid = threadIdx.x;
    const float* xr = x + (size_t)row * DMODEL;
    float v0 = xr[tid], v1 = xr[tid + 256];
    float s = v0 + v1, s2 = v0 * v0 + v1 * v1;
    for (int off = 32; off; off >>= 1) {
        s += __shfl_down(s, off);
        s2 += __shfl_down(s2, off);
    }
    __shared__ float ls[4], ls2[4];
    int wid = tid >> 6;
    if ((tid & 63) == 0) { ls[wid] = s; ls2[wid] = s2; }
    __syncthreads();
    s = ls[0] + ls[1] + ls[2] + ls[3];
    s2 = ls2[0] + ls2[1] + ls2[2] + ls2[3];
    float mean = s * (1.0f / DMODEL);
    float var = s2 * (1.0f / DMODEL) - mean * mean;
    float r = rsqrtf(var + 1e-5f);
    float o0 = (v0 - mean) * r * gp[tid] + bp[tid];
    float o1 = (v1 - mean) * r * gp[tid + 256] + bp[tid + 256];
    size_t i0 = (size_t)row * DMODEL + tid;
    if (f) { ((float*)out)[i0] = o0; ((float*)out)[i0 + 256] = o1; }
    else   { ((u16*)out)[i0] = f2b(o0); ((u16*)out)[i0 + 256] = f2b(o1); }
}

// ================= MFMA GEMM: C[M][N] = [res +] act(A[M][K] @ BT[N][K]^T + bias) =================
// A, BT bf16; bias fp32; res fp32 (may alias C when fp32 out).
// 128x128 tile, BK=32, 4 waves (2x2), each wave 4x4 of mfma_f32_16x16x32_bf16.
template <int ACT, int RES, int OUTBF>
__global__ __launch_bounds__(256) void gemm_mfma(const u16* __restrict__ A,
                                                 const u16* __restrict__ BT,
                                                 const float* __restrict__ bias,
                                                 const float* __restrict__ res,
                                                 void* __restrict__ Cp,
                                                 int M, int N, int K) {
    __shared__ u16 As[128][32];
    __shared__ u16 Bs[128][32];
    const int m0 = blockIdx.y * 128, n0 = blockIdx.x * 128;
    const int tid = threadIdx.x, lane = tid & 63, wid = tid >> 6;
    const int wm = (wid >> 1) << 6, wn = (wid & 1) << 6;
    const int quad = lane >> 4, low = lane & 15;
    const int srow = tid >> 2, scol = (tid & 3) * 8;  // staging: 16B chunk per thread
    f4 acc[4][4] = {};
    for (int k0 = 0; k0 < K; k0 += 32) {
        // stage A and BT tiles: 2 chunks each (rows srow and srow+64)
        uint4 a0 = *(const uint4*)(A + (size_t)(m0 + srow) * K + k0 + scol);
        uint4 a1 = *(const uint4*)(A + (size_t)(m0 + 64 + srow) * K + k0 + scol);
        uint4 b0 = *(const uint4*)(BT + (size_t)(n0 + srow) * K + k0 + scol);
        uint4 b1 = *(const uint4*)(BT + (size_t)(n0 + 64 + srow) * K + k0 + scol);
        *(uint4*)((char*)&As[0][0] + (size_t)tid * 16) = a0;
        *(uint4*)((char*)&As[0][0] + 4096 + (size_t)tid * 16) = a1;
        *(uint4*)((char*)&Bs[0][0] + (size_t)tid * 16) = b0;
        *(uint4*)((char*)&Bs[0][0] + 4096 + (size_t)tid * 16) = b1;
        __syncthreads();
        b8 af[4], bfr[4];
#pragma unroll
        for (int i = 0; i < 4; i++)
            af[i] = *(const b8*)&As[wm + i * 16 + low][quad * 8];
#pragma unroll
        for (int j = 0; j < 4; j++)
            bfr[j] = *(const b8*)&Bs[wn + j * 16 + low][quad * 8];
#pragma unroll
        for (int i = 0; i < 4; i++)
#pragma unroll
            for (int j = 0; j < 4; j++)
                acc[i][j] = __builtin_amdgcn_mfma_f32_16x16x32_bf16(af[i], bfr[j], acc[i][j], 0, 0, 0);
        __syncthreads();
    }
    // epilogue: D row = quad*4+r, col = low (m89/m91-verified layout)
#pragma unroll
    for (int i = 0; i < 4; i++) {
#pragma unroll
        for (int j = 0; j < 4; j++) {
            int gn = n0 + wn + j * 16 + low;
            float bv = bias[gn];
#pragma unroll
            for (int r = 0; r < 4; r++) {
                int gm = m0 + wm + i * 16 + quad * 4 + r;
                float v = acc[i][j][r] + bv;
                if (ACT) v = 0.5f * v * (1.0f + erff(v * 0.70710678f));
                if (RES) v += res[(size_t)gm * N + gn];
                if (OUTBF) ((u16*)Cp)[(size_t)gm * N + gn] = f2b(v);
                else       ((float*)Cp)[(size_t)gm * N + gn] = v;
            }
        }
    }
}

// ================= flash attention: block = (i-tile 32, h, b), online softmax =================
__global__ __launch_bounds__(256) void attn_flash(const u16* __restrict__ qkv,  // [R][1536]
                                                  const float* __restrict__ cf, // [R][3]
                                                  const float* __restrict__ inv_std,
                                                  const float* __restrict__ tempF, int l,
                                                  u16* __restrict__ o) {        // [R][512]
    const int it = blockIdx.x, h = blockIdx.y, b = blockIdx.z;
    const int i0 = it * 32, tid = threadIdx.x;
    __shared__ float Qs[64][34];   // [d][i], pre-scaled
    __shared__ float Ks[64][68];   // [d][j]
    __shared__ float Vs[64][68];   // [j][d]
    __shared__ float Ps[64][34];   // [j][i]
    __shared__ float s_ci[32][3], s_cj[64][3];
    __shared__ float s_m[32], s_l[32], s_alpha[32];
    const size_t rbase = (size_t)b * NTOK;
    {   // stage Q (32x64), scaled by 1/sqrt(dh)
        int i = tid >> 3, dc = (tid & 7) * 8;
        const u16* qp = qkv + (rbase + i0 + i) * 1536 + h * 64 + dc;
        uint4 qv = *(const uint4*)qp;
        const u16* qe = (const u16*)&qv;
#pragma unroll
        for (int e = 0; e < 8; e++) Qs[dc + e][i] = bf2f(qe[e]) * 0.125f;
    }
    if (tid < 32) {
        s_m[tid] = -1e30f; s_l[tid] = 0.f;
        s_ci[tid][0] = cf[(rbase + i0 + tid) * 3 + 0];
        s_ci[tid][1] = cf[(rbase + i0 + tid) * 3 + 1];
        s_ci[tid][2] = cf[(rbase + i0 + tid) * 3 + 2];
    }
    float t0 = tempF[l * 8 + h];
    float w = (fmaxf(t0, 0.f) + log1pf(__expf(-fabsf(t0)))) * inv_std[b];
    const int tx = tid & 15, ty = tid >> 4;   // micro-tile mapping (S and PV)
    const int ip = tid >> 3, part = tid & 7;  // row-stats mapping
    float oacc[2][4] = {{0, 0, 0, 0}, {0, 0, 0, 0}};
    for (int jt = 0; jt < 16; jt++) {
        const int j0 = jt * 64;
        __syncthreads();
        {   // stage K (transposed) and V tiles
            int j = tid >> 2, dc = (tid & 3) * 16;
            const u16* kp = qkv + (rbase + j0 + j) * 1536 + 512 + h * 64 + dc;
            const u16* vp = qkv + (rbase + j0 + j) * 1536 + 1024 + h * 64 + dc;
            uint4 k0v = *(const uint4*)kp, k1v = *(const uint4*)(kp + 8);
            uint4 v0v = *(const uint4*)vp, v1v = *(const uint4*)(vp + 8);
            const u16* ke = (const u16*)&k0v;
            const u16* ke2 = (const u16*)&k1v;
            const u16* ve = (const u16*)&v0v;
            const u16* ve2 = (const u16*)&v1v;
#pragma unroll
            for (int e = 0; e < 8; e++) {
                Ks[dc + e][j] = bf2f(ke[e]);
                Ks[dc + 8 + e][j] = bf2f(ke2[e]);
                Vs[j][dc + e] = bf2f(ve[e]);
                Vs[j][dc + 8 + e] = bf2f(ve2[e]);
            }
            if (tid < 64) {
                s_cj[tid][0] = cf[(rbase + j0 + tid) * 3 + 0] + 1e-5f;
                s_cj[tid][1] = cf[(rbase + j0 + tid) * 3 + 1] + 1e-5f;
                s_cj[tid][2] = cf[(rbase + j0 + tid) * 3 + 2] + 1e-5f;
            }
        }
        __syncthreads();
        // S = Q.K^T micro (2i x 4j per thread)
        float s[2][4] = {{0, 0, 0, 0}, {0, 0, 0, 0}};
#pragma unroll 8
        for (int kk = 0; kk < 64; kk++) {
            float2 a = *(const float2*)&Qs[kk][ty * 2];
            float4 bv = *(const float4*)&Ks[kk][tx * 4];
            s[0][0] += a.x * bv.x; s[0][1] += a.x * bv.y; s[0][2] += a.x * bv.z; s[0][3] += a.x * bv.w;
            s[1][0] += a.y * bv.x; s[1][1] += a.y * bv.y; s[1][2] += a.y * bv.z; s[1][3] += a.y * bv.w;
        }
#pragma unroll
        for (int ii = 0; ii < 2; ii++) {
            int i = ty * 2 + ii;
            float cx = s_ci[i][0], cy = s_ci[i][1], cz = s_ci[i][2];
#pragma unroll
            for (int jj = 0; jj < 4; jj++) {
                int j = tx * 4 + jj;
                float dx = cx - s_cj[j][0], dy = cy - s_cj[j][1], dz = cz - s_cj[j][2];
                Ps[j][i] = s[ii][jj] - w * sqrtf(dx * dx + dy * dy + dz * dz);
            }
        }
        __syncthreads();
        // online-softmax row stats: 8 lanes per row (same wave octet)
        float mx = -1e30f;
#pragma unroll
        for (int jj = 0; jj < 8; jj++) mx = fmaxf(mx, Ps[part * 8 + jj][ip]);
        mx = fmaxf(mx, __shfl_xor(mx, 1));
        mx = fmaxf(mx, __shfl_xor(mx, 2));
        mx = fmaxf(mx, __shfl_xor(mx, 4));
        float mold = s_m[ip];
        float mnew = fmaxf(mold, mx);
        float alpha = __expf(mold - mnew);
        float psum = 0.f;
#pragma unroll
        for (int jj = 0; jj < 8; jj++) {
            float p = __expf(Ps[part * 8 + jj][ip] - mnew);
            Ps[part * 8 + jj][ip] = p;
            psum += p;
        }
        psum += __shfl_xor(psum, 1);
        psum += __shfl_xor(psum, 2);
        psum += __shfl_xor(psum, 4);
        if (part == 0) {
            s_m[ip] = mnew;
            s_l[ip] = s_l[ip] * alpha + psum;
            s_alpha[ip] = alpha;
        }
        __syncthreads();
        // O += P.V micro (2i x 4d per thread), with rescale
        float al0 = s_alpha[ty * 2], al1 = s_alpha[ty * 2 + 1];
#pragma unroll
        for (int d2 = 0; d2 < 4; d2++) { oacc[0][d2] *= al0; oacc[1][d2] *= al1; }
#pragma unroll 8
        for (int j = 0; j < 64; j++) {
            float2 p = *(const float2*)&Ps[j][ty * 2];
            float4 vv = *(const float4*)&Vs[j][tx * 4];
            oacc[0][0] += p.x * vv.x; oacc[0][1] += p.x * vv.y; oacc[0][2] += p.x * vv.z; oacc[0][3] += p.x * vv.w;
            oacc[1][0] += p.y * vv.x; oacc[1][1] += p.y * vv.y; oacc[1][2] += p.y * vv.z; oacc[1][3] += p.y * vv.w;
        }
    }
#pragma unroll
    for (int ii = 0; ii < 2; ii++) {
        int i = ty * 2 + ii;
        float rl = 1.f / s_l[i];
        u16* op = o + (rbase + i0 + i) * 512 + h * 64 + tx * 4;
#pragma unroll
        for (int d2 = 0; d2 < 4; d2++) op[d2] = f2b(oacc[ii][d2] * rl);
    }
}

extern "C" void kernel_launch(void* const* d_in, const int* in_sizes, int n_in,
                              void* d_out, int out_size, void* d_ws, size_t ws_size,
                              hipStream_t stream) {
    const void* phi    = d_in[0];
    const void* coords = d_in[1];
    const void* modes  = d_in[2];
    const void* We     = d_in[3];
    const void* be     = d_in[4];
    const void* wq     = d_in[5];
    const void* bq     = d_in[6];
    const void* wk     = d_in[7];
    const void* bk     = d_in[8];
    const void* wv     = d_in[9];
    const void* bv     = d_in[10];
    const void* wo     = d_in[11];
    const void* bo     = d_in[12];
    const void* temp   = d_in[13];
    const void* ln1g   = d_in[14];
    const void* ln1b   = d_in[15];
    const void* ln2g   = d_in[16];
    const void* ln2b   = d_in[17];
    const void* w1     = d_in[18];
    const void* b1     = d_in[19];
    const void* w2     = d_in[20];
    const void* b2     = d_in[21];
    const void* fng    = d_in[22];
    const void* fnb    = d_in[23];

    const int R = BATCH * NTOK;  // 2048
    char* ws = (char*)d_ws;
    const size_t MB = 1u << 20;
    float* xf   = (float*)(ws);                 // [2048][512] fp32   4 MB
    u16*  yf    = (u16*)(ws + 4 * MB);          // [2048][512] bf16   2 MB
    u16*  of    = (u16*)(ws + 6 * MB);          // [2048][512] bf16   2 MB
    u16*  pool  = (u16*)(ws + 8 * MB);          // 8 MB: ff | qkv | hf
    u16*  ff    = pool;                         // [2048][512]
    u16*  qkvb  = pool;                         // [2048][1536]
    u16*  hf    = pool;                         // [2048][2048]
    u16*  WeT   = (u16*)(ws + 16 * MB);         // [512][512]        0.5 MB
    u16*  wqkvT = (u16*)(ws + 16 * MB + 512 * 1024);   // [4][1536][512] 6 MB
    u16*  woT   = (u16*)(ws + 22 * MB + 512 * 1024);   // [4][512][512]  2 MB
    u16*  w1T   = (u16*)(ws + 24 * MB + 512 * 1024);   // [4][2048][512] 8 MB
    u16*  w2T   = (u16*)(ws + 32 * MB + 512 * 1024);   // [4][512][2048] 8 MB
    float* prm  = (float*)(ws + 40 * MB + 512 * 1024); // OB_TOTAL floats ~113 KB
    float* cf   = (float*)(ws + 41 * MB);              // [2048][3] fp32 24 KB
    float* part = (float*)(ws + 41 * MB + 128 * 1024); // 4096 floats
    float* inv_std = (float*)(ws + 41 * MB + 192 * 1024);
    int*   flag = (int*)(ws + 41 * MB + 192 * 1024 + 64);

    // ---- prep ----
    detect_kernel<<<1, 256, 0, stream>>>(wq, flag);
    cvt_all_kernel<<<(R * DMODEL + 255) / 256, 256, 0, stream>>>(phi, coords, xf, cf, flag);
    pack_params<<<32, 256, 0, stream>>>(be, bq, bk, bv, bo, b1, b2, temp,
                                        ln1g, ln1b, ln2g, ln2b, fng, fnb, modes, prm, flag);
    tr_qkv<<<dim3(16, 16, 12), 256, 0, stream>>>(wq, wk, wv, wqkvT, flag);
    tr_woWe<<<dim3(16, 16, 5), 256, 0, stream>>>(wo, We, woT, WeT, flag);
    tr_gen<<<dim3(64, 16, 4), 256, 0, stream>>>(w1, w1T, 512, 2048, flag);  // [512][2048]->[2048][512]
    tr_gen<<<dim3(16, 64, 4), 256, 0, stream>>>(w2, w2T, 2048, 512, flag);  // [2048][512]->[512][2048]

    // ---- encode: xf = phi + ff @ We + be ----
    feats_kernel<<<R, 256, 0, stream>>>(cf, prm + OB_MODES, ff);
    gemm_mfma<0, 1, 0><<<dim3(4, 16), 256, 0, stream>>>(ff, WeT, prm + OB_BE, xf, xf,
                                                        R, DMODEL, DMODEL);
    // ---- distance inv-std ----
    dstat_kernel<<<R, 256, 0, stream>>>(cf, part);
    dreduce_kernel<<<BATCH, 256, 0, stream>>>(part, inv_std);

    for (int l = 0; l < NLAYER; l++) {
        ln_bf_kernel<<<R, 256, 0, stream>>>(xf, prm + OB_L1G + l * 512, prm + OB_L1B + l * 512, yf);
        gemm_mfma<0, 0, 1><<<dim3(12, 16), 256, 0, stream>>>(
            yf, wqkvT + (size_t)l * 1536 * 512, prm + OB_BQKV + l * 1536, nullptr, qkvb,
            R, 1536, DMODEL);
        attn_flash<<<dim3(32, NHEAD, BATCH), 256, 0, stream>>>(qkvb, cf, inv_std,
                                                               prm + OB_TEMP, l, of);
        gemm_mfma<0, 1, 0><<<dim3(4, 16), 256, 0, stream>>>(
            of, woT + (size_t)l * 512 * 512, prm + OB_BO + l * 512, xf, xf, R, DMODEL, DMODEL);
        ln_bf_kernel<<<R, 256, 0, stream>>>(xf, prm + OB_L2G + l * 512, prm + OB_L2B + l * 512, yf);
        gemm_mfma<1, 0, 1><<<dim3(16, 16), 256, 0, stream>>>(
            yf, w1T + (size_t)l * 2048 * 512, prm + OB_B1 + l * 2048, nullptr, hf,
            R, DFFN, DMODEL);
        gemm_mfma<0, 1, 0><<<dim3(4, 16), 256, 0, stream>>>(
            hf, w2T + (size_t)l * 512 * 2048, prm + OB_B2 + l * 512, xf, xf, R, DMODEL, DFFN);
    }
    ln_out_kernel<<<R, 256, 0, stream>>>(xf, prm + OB_FNG, prm + OB_FNB, d_out, flag);
}

// Round 4
// 705.556 us; speedup vs baseline: 11.5008x; 1.4754x over previous
//
#include <hip/hip_runtime.h>
#include <hip/hip_bf16.h>
#include <math.h>

#define BATCH 2
#define NTOK 1024
#define DMODEL 512
#define NHEAD 8
#define DH 64
#define NLAYER 4
#define MMODES 256
#define DFFN 2048

typedef unsigned short u16;
typedef __attribute__((ext_vector_type(4))) float f4;
typedef __attribute__((ext_vector_type(8))) short b8;

__device__ __forceinline__ float bf2f(u16 u) { return __uint_as_float(((unsigned)u) << 16); }
__device__ __forceinline__ u16 f2b(float x) {
    unsigned u = __float_as_uint(x);
    return (u16)((u + 0x7FFF + ((u >> 16) & 1)) >> 16);
}
// dtype-flexible load from raw input buffers: f32!=0 -> float32, else bf16
__device__ __forceinline__ float ldx(const void* p, size_t i, int f32) {
    return f32 ? ((const float*)p)[i] : bf2f(((const u16*)p)[i]);
}

// ================= dtype probe (verified working) =================
__global__ __launch_bounds__(256) void detect_kernel(const void* __restrict__ probe,
                                                     int* __restrict__ flag) {
    const u16* u = (const u16*)probe;
    int big = 0, zer = 0;
    for (int t = threadIdx.x; t < 768; t += 256) {
        u16 w = u[2 * t];
        int e = (w >> 7) & 0xFF;
        if (e >= 137) big++;
        if (w == 0) zer++;
    }
    __shared__ int sb, sz;
    if (threadIdx.x == 0) { sb = 0; sz = 0; }
    __syncthreads();
    atomicAdd(&sb, big);
    atomicAdd(&sz, zer);
    __syncthreads();
    if (threadIdx.x == 0) flag[0] = (sb >= 64 || sz >= 700) ? 1 : 0;
}

// ================= convert phi -> xf (fp32) and coords -> cf (fp32) =================
__global__ __launch_bounds__(256) void cvt_all_kernel(const void* __restrict__ phi,
                                                      const void* __restrict__ coords,
                                                      float* __restrict__ xf,
                                                      float* __restrict__ cf,
                                                      const int* __restrict__ fl) {
    int f = fl[0];
    int i = blockIdx.x * 256 + threadIdx.x;
    if (i < BATCH * NTOK * DMODEL) xf[i] = ldx(phi, i, f);
    if (i < BATCH * NTOK * 3) cf[i] = ldx(coords, i, f);
}

// ================= pack all small params to fp32 =================
#define OB_BE 0
#define OB_BQKV 512
#define OB_BO 6656
#define OB_B1 8704
#define OB_B2 16896
#define OB_TEMP 18944
#define OB_L1G 18976
#define OB_L1B 21024
#define OB_L2G 23072
#define OB_L2B 25120
#define OB_FNG 27168
#define OB_FNB 27680
#define OB_MODES 28192
#define OB_TOTAL 28960
__global__ __launch_bounds__(256) void pack_params(
    const void* be_, const void* bq_, const void* bk_, const void* bv_,
    const void* bo_, const void* b1_, const void* b2_, const void* temp_,
    const void* l1g_, const void* l1b_, const void* l2g_, const void* l2b_,
    const void* fng_, const void* fnb_, const void* modes_,
    float* __restrict__ out, const int* __restrict__ fl) {
    int f = fl[0];
    for (int idx = blockIdx.x * 256 + threadIdx.x; idx < OB_TOTAL; idx += gridDim.x * 256) {
        float v;
        int i = idx;
        if (i < 512) v = ldx(be_, i, f);
        else if ((i -= 512) < 6144) {
            int l = i / 1536, r = i - l * 1536;
            v = (r < 512) ? ldx(bq_, (size_t)l * 512 + r, f)
              : (r < 1024) ? ldx(bk_, (size_t)l * 512 + r - 512, f)
              : ldx(bv_, (size_t)l * 512 + r - 1024, f);
        }
        else if ((i -= 6144) < 2048) v = ldx(bo_, i, f);
        else if ((i -= 2048) < 8192) v = ldx(b1_, i, f);
        else if ((i -= 8192) < 2048) v = ldx(b2_, i, f);
        else if ((i -= 2048) < 32)   v = ldx(temp_, i, f);
        else if ((i -= 32) < 2048)   v = ldx(l1g_, i, f);
        else if ((i -= 2048) < 2048) v = ldx(l1b_, i, f);
        else if ((i -= 2048) < 2048) v = ldx(l2g_, i, f);
        else if ((i -= 2048) < 2048) v = ldx(l2b_, i, f);
        else if ((i -= 2048) < 512)  v = ldx(fng_, i, f);
        else if ((i -= 512) < 512)   v = ldx(fnb_, i, f);
        else { i -= 512; v = ldx(modes_, i, f); }
        out[idx] = v;
    }
}

// ================= weight transpose to bf16 W^T [C][R] from src [R][C] =================
__device__ __forceinline__ void tr_body(const void* src, size_t sbase, u16* dst,
                                        size_t dbase, int R, int C, int dstRowOff, int f) {
    __shared__ float t[32][33];
    int c0 = blockIdx.x * 32, r0 = blockIdx.y * 32;
    int tx = threadIdx.x & 31, ty8 = threadIdx.x >> 5;
#pragma unroll
    for (int rr = 0; rr < 4; rr++) {
        int r = r0 + ty8 + rr * 8;
        t[ty8 + rr * 8][tx] = ldx(src, sbase + (size_t)r * C + c0 + tx, f);
    }
    __syncthreads();
#pragma unroll
    for (int rr = 0; rr < 4; rr++) {
        int c = c0 + ty8 + rr * 8;
        dst[dbase + (size_t)(dstRowOff + c) * R + r0 + tx] = f2b(t[tx][ty8 + rr * 8]);
    }
}
__global__ __launch_bounds__(256) void tr_qkv(const void* wq_, const void* wk_,
                                              const void* wv_, u16* dst,
                                              const int* __restrict__ fl) {
    int z = blockIdx.z, l = z / 3, mat = z - l * 3;
    const void* s = (mat == 0) ? wq_ : (mat == 1) ? wk_ : wv_;
    tr_body(s, (size_t)l * 512 * 512, dst, (size_t)l * 1536 * 512, 512, 512, mat * 512, fl[0]);
}
__global__ __launch_bounds__(256) void tr_woWe(const void* wo_, const void* We_,
                                               u16* woT, u16* WeT,
                                               const int* __restrict__ fl) {
    int z = blockIdx.z;
    if (z < 4) tr_body(wo_, (size_t)z * 512 * 512, woT, (size_t)z * 512 * 512, 512, 512, 0, fl[0]);
    else       tr_body(We_, 0, WeT, 0, 512, 512, 0, fl[0]);
}
__global__ __launch_bounds__(256) void tr_gen(const void* src, u16* dst, int R, int C,
                                              const int* __restrict__ fl) {
    int z = blockIdx.z;
    tr_body(src, (size_t)z * R * C, dst, (size_t)z * R * C, R, C, 0, fl[0]);
}

// ================= Fourier features -> bf16 =================
__global__ __launch_bounds__(256) void feats_kernel(const float* __restrict__ cf,
                                                    const float* __restrict__ modesF,
                                                    u16* __restrict__ ff) {
    int row = blockIdx.x, m = threadIdx.x;
    float cx = cf[row * 3 + 0], cy = cf[row * 3 + 1], cz = cf[row * 3 + 2];
    float ph = cx * modesF[m * 3 + 0] + cy * modesF[m * 3 + 1] + cz * modesF[m * 3 + 2];
    ff[(size_t)row * 512 + m] = f2b(cosf(ph));
    ff[(size_t)row * 512 + MMODES + m] = f2b(sinf(ph));
}

// ================= distance stats (ddof=1 inv-std per batch) =================
__global__ __launch_bounds__(256) void dstat_kernel(const float* __restrict__ cf,
                                                    float* __restrict__ part) {
    int b = blockIdx.x >> 10, i = blockIdx.x & 1023;
    const float* cb = cf + (size_t)b * NTOK * 3;
    float xi = cb[i * 3], yi = cb[i * 3 + 1], zi = cb[i * 3 + 2];
    float ls = 0.f, ls2 = 0.f;
    for (int j = threadIdx.x; j < NTOK; j += 256) {
        float dx = xi - (cb[j * 3] + 1e-5f);
        float dy = yi - (cb[j * 3 + 1] + 1e-5f);
        float dz = zi - (cb[j * 3 + 2] + 1e-5f);
        float d = sqrtf(dx * dx + dy * dy + dz * dz);
        ls += d; ls2 += d * d;
    }
    for (int off = 32; off; off >>= 1) {
        ls += __shfl_down(ls, off);
        ls2 += __shfl_down(ls2, off);
    }
    __shared__ float rs[4], rs2[4];
    int wid = threadIdx.x >> 6;
    if ((threadIdx.x & 63) == 0) { rs[wid] = ls; rs2[wid] = ls2; }
    __syncthreads();
    if (threadIdx.x == 0) {
        part[blockIdx.x] = rs[0] + rs[1] + rs[2] + rs[3];
        part[2048 + blockIdx.x] = rs2[0] + rs2[1] + rs2[2] + rs2[3];
    }
}
__global__ __launch_bounds__(256) void dreduce_kernel(const float* __restrict__ part,
                                                      float* __restrict__ inv_std) {
    int b = blockIdx.x;
    double s = 0.0, s2 = 0.0;
    for (int t = threadIdx.x; t < NTOK; t += 256) {
        s += (double)part[b * NTOK + t];
        s2 += (double)part[2048 + b * NTOK + t];
    }
    for (int off = 32; off; off >>= 1) {
        s += __shfl_down(s, off);
        s2 += __shfl_down(s2, off);
    }
    __shared__ double ds[4], ds2[4];
    int wid = threadIdx.x >> 6;
    if ((threadIdx.x & 63) == 0) { ds[wid] = s; ds2[wid] = s2; }
    __syncthreads();
    if (threadIdx.x == 0) {
        double S = ds[0] + ds[1] + ds[2] + ds[3];
        double S2 = ds2[0] + ds2[1] + ds2[2] + ds2[3];
        double n = (double)NTOK * (double)NTOK;
        double mean = S / n;
        double var = (S2 - n * mean * mean) / (n - 1.0);
        inv_std[b] = (float)(1.0 / sqrt(var));
    }
}

// ================= LayerNorm: fp32 in -> bf16 out =================
__global__ __launch_bounds__(256) void ln_bf_kernel(const float* __restrict__ x,
                                                    const float* __restrict__ gp,
                                                    const float* __restrict__ bp,
                                                    u16* __restrict__ y) {
    int row = blockIdx.x, tid = threadIdx.x;
    const float* xr = x + (size_t)row * DMODEL;
    float v0 = xr[tid], v1 = xr[tid + 256];
    float s = v0 + v1, s2 = v0 * v0 + v1 * v1;
    for (int off = 32; off; off >>= 1) {
        s += __shfl_down(s, off);
        s2 += __shfl_down(s2, off);
    }
    __shared__ float ls[4], ls2[4];
    int wid = tid >> 6;
    if ((tid & 63) == 0) { ls[wid] = s; ls2[wid] = s2; }
    __syncthreads();
    s = ls[0] + ls[1] + ls[2] + ls[3];
    s2 = ls2[0] + ls2[1] + ls2[2] + ls2[3];
    float mean = s * (1.0f / DMODEL);
    float var = s2 * (1.0f / DMODEL) - mean * mean;
    float r = rsqrtf(var + 1e-5f);
    y[(size_t)row * DMODEL + tid] = f2b((v0 - mean) * r * gp[tid] + bp[tid]);
    y[(size_t)row * DMODEL + tid + 256] = f2b((v1 - mean) * r * gp[tid + 256] + bp[tid + 256]);
}
__global__ __launch_bounds__(256) void ln_out_kernel(const float* __restrict__ x,
                                                     const float* __restrict__ gp,
                                                     const float* __restrict__ bp,
                                                     void* __restrict__ out,
                                                     const int* __restrict__ fl) {
    int f = fl[0];
    int row = blockIdx.x, tid = threadIdx.x;
    const float* xr = x + (size_t)row * DMODEL;
    float v0 = xr[tid], v1 = xr[tid + 256];
    float s = v0 + v1, s2 = v0 * v0 + v1 * v1;
    for (int off = 32; off; off >>= 1) {
        s += __shfl_down(s, off);
        s2 += __shfl_down(s2, off);
    }
    __shared__ float ls[4], ls2[4];
    int wid = tid >> 6;
    if ((tid & 63) == 0) { ls[wid] = s; ls2[wid] = s2; }
    __syncthreads();
    s = ls[0] + ls[1] + ls[2] + ls[3];
    s2 = ls2[0] + ls2[1] + ls2[2] + ls2[3];
    float mean = s * (1.0f / DMODEL);
    float var = s2 * (1.0f / DMODEL) - mean * mean;
    float r = rsqrtf(var + 1e-5f);
    float o0 = (v0 - mean) * r * gp[tid] + bp[tid];
    float o1 = (v1 - mean) * r * gp[tid + 256] + bp[tid + 256];
    size_t i0 = (size_t)row * DMODEL + tid;
    if (f) { ((float*)out)[i0] = o0; ((float*)out)[i0 + 256] = o1; }
    else   { ((u16*)out)[i0] = f2b(o0); ((u16*)out)[i0 + 256] = f2b(o1); }
}

// ================= MFMA GEMM, templated tile: BM=32*FM, BN=32*FN, BK=32 =================
// C[M][N] = [res +] act(A[M][K] @ BT[N][K]^T + bias). 4 waves as 2x2; wave does FM x FN frags.
template <int FM, int FN, int ACT, int RES, int OUTBF>
__global__ __launch_bounds__(256) void gemm_mfma(const u16* __restrict__ A,
                                                 const u16* __restrict__ BT,
                                                 const float* __restrict__ bias,
                                                 const float* __restrict__ res,
                                                 void* __restrict__ Cp,
                                                 int M, int N, int K) {
    constexpr int BM = 32 * FM, BN = 32 * FN;
    constexpr int PA = BM / 64, PB = BN / 64;  // staging passes (2048 elem each)
    __shared__ u16 As[BM * 32];
    __shared__ u16 Bs[BN * 32];
    const int m0 = blockIdx.y * BM, n0 = blockIdx.x * BN;
    const int tid = threadIdx.x, lane = tid & 63, wid = tid >> 6;
    const int wm = (wid >> 1) * (16 * FM), wn = (wid & 1) * (16 * FN);
    const int quad = lane >> 4, low = lane & 15;
    const int srow = tid >> 2, scol = (tid & 3) * 8;
    f4 acc[FM][FN] = {};
    for (int k0 = 0; k0 < K; k0 += 32) {
#pragma unroll
        for (int p = 0; p < PA; p++) {
            uint4 a = *(const uint4*)(A + (size_t)(m0 + p * 64 + srow) * K + k0 + scol);
            *(uint4*)(As + p * 2048 + tid * 8) = a;
        }
#pragma unroll
        for (int p = 0; p < PB; p++) {
            uint4 b = *(const uint4*)(BT + (size_t)(n0 + p * 64 + srow) * K + k0 + scol);
            *(uint4*)(Bs + p * 2048 + tid * 8) = b;
        }
        __syncthreads();
        b8 af[FM], bfr[FN];
#pragma unroll
        for (int i = 0; i < FM; i++)
            af[i] = *(const b8*)(As + (wm + i * 16 + low) * 32 + quad * 8);
#pragma unroll
        for (int j = 0; j < FN; j++)
            bfr[j] = *(const b8*)(Bs + (wn + j * 16 + low) * 32 + quad * 8);
#pragma unroll
        for (int i = 0; i < FM; i++)
#pragma unroll
            for (int j = 0; j < FN; j++)
                acc[i][j] = __builtin_amdgcn_mfma_f32_16x16x32_bf16(af[i], bfr[j], acc[i][j], 0, 0, 0);
        __syncthreads();
    }
#pragma unroll
    for (int i = 0; i < FM; i++) {
#pragma unroll
        for (int j = 0; j < FN; j++) {
            int gn = n0 + wn + j * 16 + low;
            float bv = bias[gn];
#pragma unroll
            for (int r = 0; r < 4; r++) {
                int gm = m0 + wm + i * 16 + quad * 4 + r;
                float v = acc[i][j][r] + bv;
                if (ACT) v = 0.5f * v * (1.0f + erff(v * 0.70710678f));
                if (RES) v += res[(size_t)gm * N + gn];
                if (OUTBF) ((u16*)Cp)[(size_t)gm * N + gn] = f2b(v);
                else       ((float*)Cp)[(size_t)gm * N + gn] = v;
            }
        }
    }
}

// ================= MFMA flash attention: block = (64-row i-tile, h, b) =================
// 4 waves, wave w owns q-rows i0+w*16..+15. K/V tiles of 64 j per iteration.
// Q frags in registers (A-layout). K staged natural [j][72]; V staged transposed [d][72];
// P round-trips LDS in bf16 (C-layout -> A-layout). Softmax stats in registers.
__global__ __launch_bounds__(256) void attn_mfma(const u16* __restrict__ qkv,  // [R][1536]
                                                 const float* __restrict__ cf, // [R][3]
                                                 const float* __restrict__ inv_std,
                                                 const float* __restrict__ tempF, int l,
                                                 u16* __restrict__ o) {        // [R][512]
    const int it = blockIdx.x, h = blockIdx.y, b = blockIdx.z;
    const int i0 = it * 64, tid = threadIdx.x;
    const int lane = tid & 63, wid = tid >> 6;
    const int quad = lane >> 4, low = lane & 15;
    __shared__ u16 Ks[64][72];      // K natural [j][d], pad->2-way-free b128 reads
    __shared__ u16 Vs[64][72];      // V transposed [d][j]
    __shared__ u16 Ps[4][16][72];   // per-wave P [i][j]
    __shared__ float s_ci[64][3], s_cj[64][3];
    const size_t rbase = (size_t)b * NTOK;
    // Q A-frags: A[m=low][k=quad*8+e], rows i0+wid*16+low
    b8 qf[2];
    {
        const u16* qp = qkv + (rbase + i0 + wid * 16 + low) * 1536 + h * 64;
        qf[0] = *(const b8*)(qp + quad * 8);
        qf[1] = *(const b8*)(qp + 32 + quad * 8);
    }
    if (tid < 64) {
        s_ci[tid][0] = cf[(rbase + i0 + tid) * 3 + 0];
        s_ci[tid][1] = cf[(rbase + i0 + tid) * 3 + 1];
        s_ci[tid][2] = cf[(rbase + i0 + tid) * 3 + 2];
    }
    float t0 = tempF[l * 8 + h];
    float spw = (fmaxf(t0, 0.f) + log1pf(__expf(-fabsf(t0)))) * inv_std[b];
    float mold[4] = {-1e30f, -1e30f, -1e30f, -1e30f};
    float lsum[4] = {0.f, 0.f, 0.f, 0.f};
    f4 oacc[4] = {};
    __syncthreads();
    float cqx[4], cqy[4], cqz[4];
#pragma unroll
    for (int r = 0; r < 4; r++) {
        int ii = wid * 16 + quad * 4 + r;
        cqx[r] = s_ci[ii][0]; cqy[r] = s_ci[ii][1]; cqz[r] = s_ci[ii][2];
    }
    for (int jt = 0; jt < 16; jt++) {
        const int j0 = jt * 64;
        __syncthreads();
        {   // stage K natural: thread -> (j=tid>>2, 16 d at dc)
            int j = tid >> 2, dc = (tid & 3) * 16;
            const u16* kp = qkv + (rbase + j0 + j) * 1536 + 512 + h * 64 + dc;
            *(uint4*)&Ks[j][dc] = *(const uint4*)kp;
            *(uint4*)&Ks[j][dc + 8] = *(const uint4*)(kp + 8);
        }
        {   // stage V^T: wave wid owns d-rows wid*16..+15, lane = j (conflict-free b16 writes)
            const u16* vp = qkv + (rbase + j0 + lane) * 1536 + 1024 + h * 64 + wid * 16;
            uint4 v0 = *(const uint4*)vp, v1 = *(const uint4*)(vp + 8);
            const u16* ve = (const u16*)&v0;
            const u16* ve2 = (const u16*)&v1;
#pragma unroll
            for (int e = 0; e < 8; e++) {
                Vs[wid * 16 + e][lane] = ve[e];
                Vs[wid * 16 + 8 + e][lane] = ve2[e];
            }
        }
        if (tid < 64) {
            s_cj[tid][0] = cf[(rbase + j0 + tid) * 3 + 0] + 1e-5f;
            s_cj[tid][1] = cf[(rbase + j0 + tid) * 3 + 1] + 1e-5f;
            s_cj[tid][2] = cf[(rbase + j0 + tid) * 3 + 2] + 1e-5f;
        }
        __syncthreads();
        // S = Q K^T (16 x 64 per wave, 4 j-blocks x 2 k-steps)
        f4 sacc[4] = {};
#pragma unroll
        for (int jb = 0; jb < 4; jb++) {
            b8 bk0 = *(const b8*)&Ks[jb * 16 + low][quad * 8];
            b8 bk1 = *(const b8*)&Ks[jb * 16 + low][32 + quad * 8];
            sacc[jb] = __builtin_amdgcn_mfma_f32_16x16x32_bf16(qf[0], bk0, sacc[jb], 0, 0, 0);
            sacc[jb] = __builtin_amdgcn_mfma_f32_16x16x32_bf16(qf[1], bk1, sacc[jb], 0, 0, 0);
        }
        // scale + distance bias (C-layout: row=quad*4+r, col=jb*16+low)
        float sv[4][4];
#pragma unroll
        for (int jb = 0; jb < 4; jb++) {
            int j = jb * 16 + low;
            float cjx = s_cj[j][0], cjy = s_cj[j][1], cjz = s_cj[j][2];
#pragma unroll
            for (int r = 0; r < 4; r++) {
                float dx = cqx[r] - cjx, dy = cqy[r] - cjy, dz = cqz[r] - cjz;
                sv[jb][r] = sacc[jb][r] * 0.125f - spw * sqrtf(dx * dx + dy * dy + dz * dz);
            }
        }
        // online softmax: row reductions across the 16-lane group (masks 1,2,4,8)
        float alpha[4];
#pragma unroll
        for (int r = 0; r < 4; r++) {
            float mx = fmaxf(fmaxf(sv[0][r], sv[1][r]), fmaxf(sv[2][r], sv[3][r]));
            mx = fmaxf(mx, __shfl_xor(mx, 1));
            mx = fmaxf(mx, __shfl_xor(mx, 2));
            mx = fmaxf(mx, __shfl_xor(mx, 4));
            mx = fmaxf(mx, __shfl_xor(mx, 8));
            float mn = fmaxf(mold[r], mx);
            alpha[r] = __expf(mold[r] - mn);
            mold[r] = mn;
            float ps = 0.f;
#pragma unroll
            for (int jb = 0; jb < 4; jb++) {
                float p = __expf(sv[jb][r] - mn);
                Ps[wid][quad * 4 + r][jb * 16 + low] = f2b(p);
                ps += p;
            }
            ps += __shfl_xor(ps, 1);
            ps += __shfl_xor(ps, 2);
            ps += __shfl_xor(ps, 4);
            ps += __shfl_xor(ps, 8);
            lsum[r] = lsum[r] * alpha[r] + ps;
        }
        // rescale O, then O += P V  (P A-frags from LDS; V B-frags from Vs=V^T)
#pragma unroll
        for (int db = 0; db < 4; db++)
#pragma unroll
            for (int r = 0; r < 4; r++) oacc[db][r] *= alpha[r];
        b8 ap0 = *(const b8*)&Ps[wid][low][quad * 8];
        b8 ap1 = *(const b8*)&Ps[wid][low][32 + quad * 8];
#pragma unroll
        for (int db = 0; db < 4; db++) {
            b8 bv0 = *(const b8*)&Vs[db * 16 + low][quad * 8];
            b8 bv1 = *(const b8*)&Vs[db * 16 + low][32 + quad * 8];
            oacc[db] = __builtin_amdgcn_mfma_f32_16x16x32_bf16(ap0, bv0, oacc[db], 0, 0, 0);
            oacc[db] = __builtin_amdgcn_mfma_f32_16x16x32_bf16(ap1, bv1, oacc[db], 0, 0, 0);
        }
    }
    // epilogue: O/l, C-layout rows quad*4+r
#pragma unroll
    for (int r = 0; r < 4; r++) {
        float rl = 1.f / lsum[r];
        u16* op = o + (rbase + i0 + wid * 16 + quad * 4 + r) * 512 + h * 64 + low;
#pragma unroll
        for (int db = 0; db < 4; db++) op[db * 16] = f2b(oacc[db][r] * rl);
    }
}

extern "C" void kernel_launch(void* const* d_in, const int* in_sizes, int n_in,
                              void* d_out, int out_size, void* d_ws, size_t ws_size,
                              hipStream_t stream) {
    const void* phi    = d_in[0];
    const void* coords = d_in[1];
    const void* modes  = d_in[2];
    const void* We     = d_in[3];
    const void* be     = d_in[4];
    const void* wq     = d_in[5];
    const void* bq     = d_in[6];
    const void* wk     = d_in[7];
    const void* bk     = d_in[8];
    const void* wv     = d_in[9];
    const void* bv     = d_in[10];
    const void* wo     = d_in[11];
    const void* bo     = d_in[12];
    const void* temp   = d_in[13];
    const void* ln1g   = d_in[14];
    const void* ln1b   = d_in[15];
    const void* ln2g   = d_in[16];
    const void* ln2b   = d_in[17];
    const void* w1     = d_in[18];
    const void* b1     = d_in[19];
    const void* w2     = d_in[20];
    const void* b2     = d_in[21];
    const void* fng    = d_in[22];
    const void* fnb    = d_in[23];

    const int R = BATCH * NTOK;  // 2048
    char* ws = (char*)d_ws;
    const size_t MB = 1u << 20;
    float* xf   = (float*)(ws);                 // [2048][512] fp32   4 MB
    u16*  yf    = (u16*)(ws + 4 * MB);          // [2048][512] bf16   2 MB
    u16*  of    = (u16*)(ws + 6 * MB);          // [2048][512] bf16   2 MB
    u16*  pool  = (u16*)(ws + 8 * MB);          // 8 MB: ff | qkv | hf
    u16*  ff    = pool;                         // [2048][512]
    u16*  qkvb  = pool;                         // [2048][1536]
    u16*  hf    = pool;                         // [2048][2048]
    u16*  WeT   = (u16*)(ws + 16 * MB);         // [512][512]        0.5 MB
    u16*  wqkvT = (u16*)(ws + 16 * MB + 512 * 1024);   // [4][1536][512] 6 MB
    u16*  woT   = (u16*)(ws + 22 * MB + 512 * 1024);   // [4][512][512]  2 MB
    u16*  w1T   = (u16*)(ws + 24 * MB + 512 * 1024);   // [4][2048][512] 8 MB
    u16*  w2T   = (u16*)(ws + 32 * MB + 512 * 1024);   // [4][512][2048] 8 MB
    float* prm  = (float*)(ws + 40 * MB + 512 * 1024); // OB_TOTAL floats
    float* cf   = (float*)(ws + 41 * MB);              // [2048][3] fp32
    float* part = (float*)(ws + 41 * MB + 128 * 1024); // 4096 floats
    float* inv_std = (float*)(ws + 41 * MB + 192 * 1024);
    int*   flag = (int*)(ws + 41 * MB + 192 * 1024 + 64);

    // ---- prep ----
    detect_kernel<<<1, 256, 0, stream>>>(wq, flag);
    cvt_all_kernel<<<(R * DMODEL + 255) / 256, 256, 0, stream>>>(phi, coords, xf, cf, flag);
    pack_params<<<32, 256, 0, stream>>>(be, bq, bk, bv, bo, b1, b2, temp,
                                        ln1g, ln1b, ln2g, ln2b, fng, fnb, modes, prm, flag);
    tr_qkv<<<dim3(16, 16, 12), 256, 0, stream>>>(wq, wk, wv, wqkvT, flag);
    tr_woWe<<<dim3(16, 16, 5), 256, 0, stream>>>(wo, We, woT, WeT, flag);
    tr_gen<<<dim3(64, 16, 4), 256, 0, stream>>>(w1, w1T, 512, 2048, flag);
    tr_gen<<<dim3(16, 64, 4), 256, 0, stream>>>(w2, w2T, 2048, 512, flag);

    // ---- encode: xf = phi + ff @ We + be ----
    feats_kernel<<<R, 256, 0, stream>>>(cf, prm + OB_MODES, ff);
    gemm_mfma<2, 2, 0, 1, 0><<<dim3(8, 32), 256, 0, stream>>>(ff, WeT, prm + OB_BE, xf, xf,
                                                              R, DMODEL, DMODEL);
    // ---- distance inv-std ----
    dstat_kernel<<<R, 256, 0, stream>>>(cf, part);
    dreduce_kernel<<<BATCH, 256, 0, stream>>>(part, inv_std);

    for (int l = 0; l < NLAYER; l++) {
        ln_bf_kernel<<<R, 256, 0, stream>>>(xf, prm + OB_L1G + l * 512, prm + OB_L1B + l * 512, yf);
        gemm_mfma<2, 4, 0, 0, 1><<<dim3(12, 32), 256, 0, stream>>>(
            yf, wqkvT + (size_t)l * 1536 * 512, prm + OB_BQKV + l * 1536, nullptr, qkvb,
            R, 1536, DMODEL);
        attn_mfma<<<dim3(16, NHEAD, BATCH), 256, 0, stream>>>(qkvb, cf, inv_std,
                                                              prm + OB_TEMP, l, of);
        gemm_mfma<2, 2, 0, 1, 0><<<dim3(8, 32), 256, 0, stream>>>(
            of, woT + (size_t)l * 512 * 512, prm + OB_BO + l * 512, xf, xf, R, DMODEL, DMODEL);
        ln_bf_kernel<<<R, 256, 0, stream>>>(xf, prm + OB_L2G + l * 512, prm + OB_L2B + l * 512, yf);
        gemm_mfma<4, 4, 1, 0, 1><<<dim3(16, 16), 256, 0, stream>>>(
            yf, w1T + (size_t)l * 2048 * 512, prm + OB_B1 + l * 2048, nullptr, hf,
            R, DFFN, DMODEL);
        gemm_mfma<2, 2, 0, 1, 0><<<dim3(8, 32), 256, 0, stream>>>(
            hf, w2T + (size_t)l * 512 * 2048, prm + OB_B2 + l * 512, xf, xf, R, DMODEL, DFFN);
    }
    ln_out_kernel<<<R, 256, 0, stream>>>(xf, prm + OB_FNG, prm + OB_FNB, d_out, flag);
}

// Round 5
// 599.509 us; speedup vs baseline: 13.5352x; 1.1769x over previous
//
#include <hip/hip_runtime.h>
#include <hip/hip_bf16.h>
#include <math.h>

#define BATCH 2
#define NTOK 1024
#define DMODEL 512
#define NHEAD 8
#define DH 64
#define NLAYER 4
#define MMODES 256
#define DFFN 2048

typedef unsigned short u16;
typedef __attribute__((ext_vector_type(4))) float f4;
typedef __attribute__((ext_vector_type(8))) short b8;

__device__ __forceinline__ float bf2f(u16 u) { return __uint_as_float(((unsigned)u) << 16); }
__device__ __forceinline__ u16 f2b(float x) {
    unsigned u = __float_as_uint(x);
    return (u16)((u + 0x7FFF + ((u >> 16) & 1)) >> 16);
}
__device__ __forceinline__ float ldx(const void* p, size_t i, int f32) {
    return f32 ? ((const float*)p)[i] : bf2f(((const u16*)p)[i]);
}
// async global->LDS, 16 B per lane; LDS dest = wave-uniform base + lane*16
__device__ __forceinline__ void async_ld16(const u16* g, u16* l) {
    __builtin_amdgcn_global_load_lds((const __attribute__((address_space(1))) void*)g,
                                     (__attribute__((address_space(3))) void*)l, 16, 0, 0);
}

// ================= dtype probe (verified) =================
__global__ __launch_bounds__(256) void detect_kernel(const void* __restrict__ probe,
                                                     int* __restrict__ flag) {
    const u16* u = (const u16*)probe;
    int big = 0, zer = 0;
    for (int t = threadIdx.x; t < 768; t += 256) {
        u16 w = u[2 * t];
        int e = (w >> 7) & 0xFF;
        if (e >= 137) big++;
        if (w == 0) zer++;
    }
    __shared__ int sb, sz;
    if (threadIdx.x == 0) { sb = 0; sz = 0; }
    __syncthreads();
    atomicAdd(&sb, big);
    atomicAdd(&sz, zer);
    __syncthreads();
    if (threadIdx.x == 0) flag[0] = (sb >= 64 || sz >= 700) ? 1 : 0;
}

// ================= convert phi/coords -> fp32 =================
__global__ __launch_bounds__(256) void cvt_all_kernel(const void* __restrict__ phi,
                                                      const void* __restrict__ coords,
                                                      float* __restrict__ xf,
                                                      float* __restrict__ cf,
                                                      const int* __restrict__ fl) {
    int f = fl[0];
    int i = blockIdx.x * 256 + threadIdx.x;
    if (i < BATCH * NTOK * DMODEL) xf[i] = ldx(phi, i, f);
    if (i < BATCH * NTOK * 3) cf[i] = ldx(coords, i, f);
}

// ================= pack small params to fp32 =================
#define OB_BE 0
#define OB_BQKV 512
#define OB_BO 6656
#define OB_B1 8704
#define OB_B2 16896
#define OB_TEMP 18944
#define OB_L1G 18976
#define OB_L1B 21024
#define OB_L2G 23072
#define OB_L2B 25120
#define OB_FNG 27168
#define OB_FNB 27680
#define OB_MODES 28192
#define OB_TOTAL 28960
__global__ __launch_bounds__(256) void pack_params(
    const void* be_, const void* bq_, const void* bk_, const void* bv_,
    const void* bo_, const void* b1_, const void* b2_, const void* temp_,
    const void* l1g_, const void* l1b_, const void* l2g_, const void* l2b_,
    const void* fng_, const void* fnb_, const void* modes_,
    float* __restrict__ out, const int* __restrict__ fl) {
    int f = fl[0];
    for (int idx = blockIdx.x * 256 + threadIdx.x; idx < OB_TOTAL; idx += gridDim.x * 256) {
        float v;
        int i = idx;
        if (i < 512) v = ldx(be_, i, f);
        else if ((i -= 512) < 6144) {
            int l = i / 1536, r = i - l * 1536;
            v = (r < 512) ? ldx(bq_, (size_t)l * 512 + r, f)
              : (r < 1024) ? ldx(bk_, (size_t)l * 512 + r - 512, f)
              : ldx(bv_, (size_t)l * 512 + r - 1024, f);
        }
        else if ((i -= 6144) < 2048) v = ldx(bo_, i, f);
        else if ((i -= 2048) < 8192) v = ldx(b1_, i, f);
        else if ((i -= 8192) < 2048) v = ldx(b2_, i, f);
        else if ((i -= 2048) < 32)   v = ldx(temp_, i, f);
        else if ((i -= 32) < 2048)   v = ldx(l1g_, i, f);
        else if ((i -= 2048) < 2048) v = ldx(l1b_, i, f);
        else if ((i -= 2048) < 2048) v = ldx(l2g_, i, f);
        else if ((i -= 2048) < 2048) v = ldx(l2b_, i, f);
        else if ((i -= 2048) < 512)  v = ldx(fng_, i, f);
        else if ((i -= 512) < 512)   v = ldx(fnb_, i, f);
        else { i -= 512; v = ldx(modes_, i, f); }
        out[idx] = v;
    }
}

// ================= weight transpose to bf16 W^T =================
__device__ __forceinline__ void tr_body(const void* src, size_t sbase, u16* dst,
                                        size_t dbase, int R, int C, int dstRowOff, int f) {
    __shared__ float t[32][33];
    int c0 = blockIdx.x * 32, r0 = blockIdx.y * 32;
    int tx = threadIdx.x & 31, ty8 = threadIdx.x >> 5;
#pragma unroll
    for (int rr = 0; rr < 4; rr++) {
        int r = r0 + ty8 + rr * 8;
        t[ty8 + rr * 8][tx] = ldx(src, sbase + (size_t)r * C + c0 + tx, f);
    }
    __syncthreads();
#pragma unroll
    for (int rr = 0; rr < 4; rr++) {
        int c = c0 + ty8 + rr * 8;
        dst[dbase + (size_t)(dstRowOff + c) * R + r0 + tx] = f2b(t[tx][ty8 + rr * 8]);
    }
}
__global__ __launch_bounds__(256) void tr_qkv(const void* wq_, const void* wk_,
                                              const void* wv_, u16* dst,
                                              const int* __restrict__ fl) {
    int z = blockIdx.z, l = z / 3, mat = z - l * 3;
    const void* s = (mat == 0) ? wq_ : (mat == 1) ? wk_ : wv_;
    tr_body(s, (size_t)l * 512 * 512, dst, (size_t)l * 1536 * 512, 512, 512, mat * 512, fl[0]);
}
__global__ __launch_bounds__(256) void tr_woWe(const void* wo_, const void* We_,
                                               u16* woT, u16* WeT,
                                               const int* __restrict__ fl) {
    int z = blockIdx.z;
    if (z < 4) tr_body(wo_, (size_t)z * 512 * 512, woT, (size_t)z * 512 * 512, 512, 512, 0, fl[0]);
    else       tr_body(We_, 0, WeT, 0, 512, 512, 0, fl[0]);
}
__global__ __launch_bounds__(256) void tr_gen(const void* src, u16* dst, int R, int C,
                                              const int* __restrict__ fl) {
    int z = blockIdx.z;
    tr_body(src, (size_t)z * R * C, dst, (size_t)z * R * C, R, C, 0, fl[0]);
}

// ================= Fourier features -> bf16 =================
__global__ __launch_bounds__(256) void feats_kernel(const float* __restrict__ cf,
                                                    const float* __restrict__ modesF,
                                                    u16* __restrict__ ff) {
    int row = blockIdx.x, m = threadIdx.x;
    float cx = cf[row * 3 + 0], cy = cf[row * 3 + 1], cz = cf[row * 3 + 2];
    float ph = cx * modesF[m * 3 + 0] + cy * modesF[m * 3 + 1] + cz * modesF[m * 3 + 2];
    ff[(size_t)row * 512 + m] = f2b(cosf(ph));
    ff[(size_t)row * 512 + MMODES + m] = f2b(sinf(ph));
}

// ================= distance stats + optional bf16 dist matrix =================
__global__ __launch_bounds__(256) void dstat_kernel(const float* __restrict__ cf,
                                                    float* __restrict__ part,
                                                    u16* __restrict__ dist) {
    int b = blockIdx.x >> 10, i = blockIdx.x & 1023;
    const float* cb = cf + (size_t)b * NTOK * 3;
    float xi = cb[i * 3], yi = cb[i * 3 + 1], zi = cb[i * 3 + 2];
    float ls = 0.f, ls2 = 0.f;
    for (int j = threadIdx.x; j < NTOK; j += 256) {
        float dx = xi - (cb[j * 3] + 1e-5f);
        float dy = yi - (cb[j * 3 + 1] + 1e-5f);
        float dz = zi - (cb[j * 3 + 2] + 1e-5f);
        float d = sqrtf(dx * dx + dy * dy + dz * dz);
        if (dist) dist[(((size_t)(b * NTOK + i)) << 10) + j] = f2b(d);
        ls += d; ls2 += d * d;
    }
    for (int off = 32; off; off >>= 1) {
        ls += __shfl_down(ls, off);
        ls2 += __shfl_down(ls2, off);
    }
    __shared__ float rs[4], rs2[4];
    int wid = threadIdx.x >> 6;
    if ((threadIdx.x & 63) == 0) { rs[wid] = ls; rs2[wid] = ls2; }
    __syncthreads();
    if (threadIdx.x == 0) {
        part[blockIdx.x] = rs[0] + rs[1] + rs[2] + rs[3];
        part[2048 + blockIdx.x] = rs2[0] + rs2[1] + rs2[2] + rs2[3];
    }
}
__global__ __launch_bounds__(256) void dreduce_kernel(const float* __restrict__ part,
                                                      float* __restrict__ inv_std) {
    int b = blockIdx.x;
    double s = 0.0, s2 = 0.0;
    for (int t = threadIdx.x; t < NTOK; t += 256) {
        s += (double)part[b * NTOK + t];
        s2 += (double)part[2048 + b * NTOK + t];
    }
    for (int off = 32; off; off >>= 1) {
        s += __shfl_down(s, off);
        s2 += __shfl_down(s2, off);
    }
    __shared__ double ds[4], ds2[4];
    int wid = threadIdx.x >> 6;
    if ((threadIdx.x & 63) == 0) { ds[wid] = s; ds2[wid] = s2; }
    __syncthreads();
    if (threadIdx.x == 0) {
        double S = ds[0] + ds[1] + ds[2] + ds[3];
        double S2 = ds2[0] + ds2[1] + ds2[2] + ds2[3];
        double n = (double)NTOK * (double)NTOK;
        double mean = S / n;
        double var = (S2 - n * mean * mean) / (n - 1.0);
        inv_std[b] = (float)(1.0 / sqrt(var));
    }
}

// ================= LayerNorm: fp32 in -> bf16 out =================
__global__ __launch_bounds__(256) void ln_bf_kernel(const float* __restrict__ x,
                                                    const float* __restrict__ gp,
                                                    const float* __restrict__ bp,
                                                    u16* __restrict__ y) {
    int row = blockIdx.x, tid = threadIdx.x;
    const float* xr = x + (size_t)row * DMODEL;
    float v0 = xr[tid], v1 = xr[tid + 256];
    float s = v0 + v1, s2 = v0 * v0 + v1 * v1;
    for (int off = 32; off; off >>= 1) {
        s += __shfl_down(s, off);
        s2 += __shfl_down(s2, off);
    }
    __shared__ float ls[4], ls2[4];
    int wid = tid >> 6;
    if ((tid & 63) == 0) { ls[wid] = s; ls2[wid] = s2; }
    __syncthreads();
    s = ls[0] + ls[1] + ls[2] + ls[3];
    s2 = ls2[0] + ls2[1] + ls2[2] + ls2[3];
    float mean = s * (1.0f / DMODEL);
    float var = s2 * (1.0f / DMODEL) - mean * mean;
    float r = rsqrtf(var + 1e-5f);
    y[(size_t)row * DMODEL + tid] = f2b((v0 - mean) * r * gp[tid] + bp[tid]);
    y[(size_t)row * DMODEL + tid + 256] = f2b((v1 - mean) * r * gp[tid + 256] + bp[tid + 256]);
}
__global__ __launch_bounds__(256) void ln_out_kernel(const float* __restrict__ x,
                                                     const float* __restrict__ gp,
                                                     const float* __restrict__ bp,
                                                     void* __restrict__ out,
                                                     const int* __restrict__ fl) {
    int f = fl[0];
    int row = blockIdx.x, tid = threadIdx.x;
    const float* xr = x + (size_t)row * DMODEL;
    float v0 = xr[tid], v1 = xr[tid + 256];
    float s = v0 + v1, s2 = v0 * v0 + v1 * v1;
    for (int off = 32; off; off >>= 1) {
        s += __shfl_down(s, off);
        s2 += __shfl_down(s2, off);
    }
    __shared__ float ls[4], ls2[4];
    int wid = tid >> 6;
    if ((tid & 63) == 0) { ls[wid] = s; ls2[wid] = s2; }
    __syncthreads();
    s = ls[0] + ls[1] + ls[2] + ls[3];
    s2 = ls2[0] + ls2[1] + ls2[2] + ls2[3];
    float mean = s * (1.0f / DMODEL);
    float var = s2 * (1.0f / DMODEL) - mean * mean;
    float r = rsqrtf(var + 1e-5f);
    float o0 = (v0 - mean) * r * gp[tid] + bp[tid];
    float o1 = (v1 - mean) * r * gp[tid + 256] + bp[tid + 256];
    size_t i0 = (size_t)row * DMODEL + tid;
    if (f) { ((float*)out)[i0] = o0; ((float*)out)[i0 + 256] = o1; }
    else   { ((u16*)out)[i0] = f2b(o0); ((u16*)out)[i0 + 256] = f2b(o1); }
}

// ================= MFMA GEMM with async global->LDS staging =================
// BM=32*FM, BN=32*FN, BK=32. C = [res +] act(A @ BT^T + bias).
template <int FM, int FN, int ACT, int RES, int OUTBF>
__global__ __launch_bounds__(256) void gemm_mfma(const u16* __restrict__ A,
                                                 const u16* __restrict__ BT,
                                                 const float* __restrict__ bias,
                                                 const float* __restrict__ res,
                                                 void* __restrict__ Cp,
                                                 int M, int N, int K) {
    constexpr int BM = 32 * FM, BN = 32 * FN;
    constexpr int PA = BM / 64, PB = BN / 64;
    __shared__ u16 As[BM * 32];
    __shared__ u16 Bs[BN * 32];
    const int m0 = blockIdx.y * BM, n0 = blockIdx.x * BN;
    const int tid = threadIdx.x, lane = tid & 63, wid = tid >> 6;
    const int wm = (wid >> 1) * (16 * FM), wn = (wid & 1) * (16 * FN);
    const int quad = lane >> 4, low = lane & 15;
    const int srow = tid >> 2, scol = (tid & 3) * 8;
    f4 acc[FM][FN] = {};
    for (int k0 = 0; k0 < K; k0 += 32) {
        // async staging: LDS dest contiguous at (wave base + lane*16)
#pragma unroll
        for (int p = 0; p < PA; p++)
            async_ld16(A + (size_t)(m0 + p * 64 + srow) * K + k0 + scol,
                       As + p * 2048 + wid * 512);
#pragma unroll
        for (int p = 0; p < PB; p++)
            async_ld16(BT + (size_t)(n0 + p * 64 + srow) * K + k0 + scol,
                       Bs + p * 2048 + wid * 512);
        __syncthreads();
        b8 af[FM], bfr[FN];
#pragma unroll
        for (int i = 0; i < FM; i++)
            af[i] = *(const b8*)(As + (wm + i * 16 + low) * 32 + quad * 8);
#pragma unroll
        for (int j = 0; j < FN; j++)
            bfr[j] = *(const b8*)(Bs + (wn + j * 16 + low) * 32 + quad * 8);
#pragma unroll
        for (int i = 0; i < FM; i++)
#pragma unroll
            for (int j = 0; j < FN; j++)
                acc[i][j] = __builtin_amdgcn_mfma_f32_16x16x32_bf16(af[i], bfr[j], acc[i][j], 0, 0, 0);
        __syncthreads();
    }
#pragma unroll
    for (int i = 0; i < FM; i++) {
#pragma unroll
        for (int j = 0; j < FN; j++) {
            int gn = n0 + wn + j * 16 + low;
            float bv = bias[gn];
#pragma unroll
            for (int r = 0; r < 4; r++) {
                int gm = m0 + wm + i * 16 + quad * 4 + r;
                float v = acc[i][j][r] + bv;
                if (ACT) v = 0.5f * v * (1.0f + erff(v * 0.70710678f));
                if (RES) v += res[(size_t)gm * N + gn];
                if (OUTBF) ((u16*)Cp)[(size_t)gm * N + gn] = f2b(v);
                else       ((float*)Cp)[(size_t)gm * N + gn] = v;
            }
        }
    }
}

// ================= MFMA flash attention v3 =================
// block = (32-row i-tile, h, b); 4 waves: group g=wid>>1 (16 rows), parity p=wid&1
// (j-tiles jt ≡ p mod 2). Per round stage both parity tiles; flash-decoding merge at end.
template <int USE_DIST>
__global__ __launch_bounds__(256) void attn_mfma(const u16* __restrict__ qkv,  // [R][1536]
                                                 const float* __restrict__ cf,
                                                 const float* __restrict__ inv_std,
                                                 const float* __restrict__ tempF, int l,
                                                 const u16* __restrict__ dist, // [B*N][N] bf16
                                                 u16* __restrict__ o) {        // [R][512]
    const int it = blockIdx.x, h = blockIdx.y, b = blockIdx.z;
    const int i0 = it * 32, tid = threadIdx.x;
    const int lane = tid & 63, wid = tid >> 6;
    const int g = wid >> 1, p = wid & 1;
    const int quad = lane >> 4, low = lane & 15;
    __shared__ u16 Ks[2][64][72];
    __shared__ u16 Vs[2][64][72];
    __shared__ u16 Ps[4][16][72];
    __shared__ float s_ci[32][3];
    __shared__ float s_cj[2][64][3];
    const size_t rbase = (size_t)b * NTOK;
    b8 qf0, qf1;
    {
        const u16* qp = qkv + (rbase + i0 + g * 16 + low) * 1536 + h * 64;
        qf0 = *(const b8*)(qp + quad * 8);
        qf1 = *(const b8*)(qp + 32 + quad * 8);
    }
    if (!USE_DIST && tid < 32) {
        s_ci[tid][0] = cf[(rbase + i0 + tid) * 3 + 0];
        s_ci[tid][1] = cf[(rbase + i0 + tid) * 3 + 1];
        s_ci[tid][2] = cf[(rbase + i0 + tid) * 3 + 2];
    }
    float t0 = tempF[l * 8 + h];
    float spw = (fmaxf(t0, 0.f) + log1pf(__expf(-fabsf(t0)))) * inv_std[b];
    float mold[4] = {-1e30f, -1e30f, -1e30f, -1e30f};
    float lsum[4] = {0.f, 0.f, 0.f, 0.f};
    f4 oacc[4] = {};
    __syncthreads();
    float cqx[4], cqy[4], cqz[4];
    const u16* drow[4];
#pragma unroll
    for (int r = 0; r < 4; r++) {
        int ii = g * 16 + quad * 4 + r;
        if (USE_DIST) drow[r] = dist + ((rbase + i0 + ii) << 10);
        else { cqx[r] = s_ci[ii][0]; cqy[r] = s_ci[ii][1]; cqz[r] = s_ci[ii][2]; }
    }
    for (int t = 0; t < 8; t++) {
        __syncthreads();
#pragma unroll
        for (int tt = 0; tt < 2; tt++) {   // stage both parity tiles
            int j0s = (t * 2 + tt) * 64;
            int j = tid >> 2, dc = (tid & 3) * 16;
            const u16* kp = qkv + (rbase + j0s + j) * 1536 + 512 + h * 64 + dc;
            *(uint4*)&Ks[tt][j][dc] = *(const uint4*)kp;
            *(uint4*)&Ks[tt][j][dc + 8] = *(const uint4*)(kp + 8);
            const u16* vp = qkv + (rbase + j0s + lane) * 1536 + 1024 + h * 64 + wid * 16;
            uint4 v0 = *(const uint4*)vp, v1 = *(const uint4*)(vp + 8);
            const u16* ve = (const u16*)&v0;
            const u16* ve2 = (const u16*)&v1;
#pragma unroll
            for (int e = 0; e < 8; e++) {
                Vs[tt][wid * 16 + e][lane] = ve[e];
                Vs[tt][wid * 16 + 8 + e][lane] = ve2[e];
            }
            if (!USE_DIST && tid < 64) {
                s_cj[tt][tid][0] = cf[(rbase + j0s + tid) * 3 + 0] + 1e-5f;
                s_cj[tt][tid][1] = cf[(rbase + j0s + tid) * 3 + 1] + 1e-5f;
                s_cj[tt][tid][2] = cf[(rbase + j0s + tid) * 3 + 2] + 1e-5f;
            }
        }
        __syncthreads();
        const int j0 = (t * 2 + p) * 64;
        // S = Q K^T (16x64 per wave)
        f4 sacc[4] = {};
#pragma unroll
        for (int jb = 0; jb < 4; jb++) {
            b8 bk0 = *(const b8*)&Ks[p][jb * 16 + low][quad * 8];
            b8 bk1 = *(const b8*)&Ks[p][jb * 16 + low][32 + quad * 8];
            sacc[jb] = __builtin_amdgcn_mfma_f32_16x16x32_bf16(qf0, bk0, sacc[jb], 0, 0, 0);
            sacc[jb] = __builtin_amdgcn_mfma_f32_16x16x32_bf16(qf1, bk1, sacc[jb], 0, 0, 0);
        }
        float sv[4][4];
#pragma unroll
        for (int jb = 0; jb < 4; jb++) {
            int j = jb * 16 + low;
            if (USE_DIST) {
#pragma unroll
                for (int r = 0; r < 4; r++)
                    sv[jb][r] = sacc[jb][r] * 0.125f - spw * bf2f(drow[r][j0 + j]);
            } else {
                float cjx = s_cj[p][j][0], cjy = s_cj[p][j][1], cjz = s_cj[p][j][2];
#pragma unroll
                for (int r = 0; r < 4; r++) {
                    float dx = cqx[r] - cjx, dy = cqy[r] - cjy, dz = cqz[r] - cjz;
                    sv[jb][r] = sacc[jb][r] * 0.125f - spw * sqrtf(dx * dx + dy * dy + dz * dz);
                }
            }
        }
        float alpha[4];
#pragma unroll
        for (int r = 0; r < 4; r++) {
            float mx = fmaxf(fmaxf(sv[0][r], sv[1][r]), fmaxf(sv[2][r], sv[3][r]));
            mx = fmaxf(mx, __shfl_xor(mx, 1));
            mx = fmaxf(mx, __shfl_xor(mx, 2));
            mx = fmaxf(mx, __shfl_xor(mx, 4));
            mx = fmaxf(mx, __shfl_xor(mx, 8));
            float mn = fmaxf(mold[r], mx);
            alpha[r] = __expf(mold[r] - mn);
            mold[r] = mn;
            float ps = 0.f;
#pragma unroll
            for (int jb = 0; jb < 4; jb++) {
                float pp = __expf(sv[jb][r] - mn);
                Ps[wid][quad * 4 + r][jb * 16 + low] = f2b(pp);
                ps += pp;
            }
            ps += __shfl_xor(ps, 1);
            ps += __shfl_xor(ps, 2);
            ps += __shfl_xor(ps, 4);
            ps += __shfl_xor(ps, 8);
            lsum[r] = lsum[r] * alpha[r] + ps;
        }
#pragma unroll
        for (int db = 0; db < 4; db++)
#pragma unroll
            for (int r = 0; r < 4; r++) oacc[db][r] *= alpha[r];
        b8 ap0 = *(const b8*)&Ps[wid][low][quad * 8];
        b8 ap1 = *(const b8*)&Ps[wid][low][32 + quad * 8];
#pragma unroll
        for (int db = 0; db < 4; db++) {
            b8 bv0 = *(const b8*)&Vs[p][db * 16 + low][quad * 8];
            b8 bv1 = *(const b8*)&Vs[p][db * 16 + low][32 + quad * 8];
            oacc[db] = __builtin_amdgcn_mfma_f32_16x16x32_bf16(ap0, bv0, oacc[db], 0, 0, 0);
            oacc[db] = __builtin_amdgcn_mfma_f32_16x16x32_bf16(ap1, bv1, oacc[db], 0, 0, 0);
        }
    }
    // ---- merge parity partials (flash-decoding style) ----
    __syncthreads();
    float* scr = (float*)&Ks[0][0][0];   // per group: 1024 O floats + 16 m + 16 l
    float* Og = scr + g * 1088;
    float* Ml = Og + 1024;
    if (p == 1) {
#pragma unroll
        for (int db = 0; db < 4; db++)
#pragma unroll
            for (int r = 0; r < 4; r++)
                Og[(quad * 4 + r) * 64 + db * 16 + low] = oacc[db][r];
        if (low == 0) {
#pragma unroll
            for (int r = 0; r < 4; r++) {
                Ml[quad * 4 + r] = mold[r];
                Ml[16 + quad * 4 + r] = lsum[r];
            }
        }
    }
    __syncthreads();
    if (p == 0) {
#pragma unroll
        for (int r = 0; r < 4; r++) {
            int row = quad * 4 + r;
            float m1 = Ml[row], l1 = Ml[16 + row];
            float mm = fmaxf(mold[r], m1);
            float a0 = __expf(mold[r] - mm), a1 = __expf(m1 - mm);
            float rl = 1.f / (lsum[r] * a0 + l1 * a1);
            u16* op = o + (rbase + i0 + g * 16 + row) * 512 + h * 64 + low;
#pragma unroll
            for (int db = 0; db < 4; db++) {
                float v = oacc[db][r] * a0 + Og[row * 64 + db * 16 + low] * a1;
                op[db * 16] = f2b(v * rl);
            }
        }
    }
}

extern "C" void kernel_launch(void* const* d_in, const int* in_sizes, int n_in,
                              void* d_out, int out_size, void* d_ws, size_t ws_size,
                              hipStream_t stream) {
    const void* phi    = d_in[0];
    const void* coords = d_in[1];
    const void* modes  = d_in[2];
    const void* We     = d_in[3];
    const void* be     = d_in[4];
    const void* wq     = d_in[5];
    const void* bq     = d_in[6];
    const void* wk     = d_in[7];
    const void* bk     = d_in[8];
    const void* wv     = d_in[9];
    const void* bv     = d_in[10];
    const void* wo     = d_in[11];
    const void* bo     = d_in[12];
    const void* temp   = d_in[13];
    const void* ln1g   = d_in[14];
    const void* ln1b   = d_in[15];
    const void* ln2g   = d_in[16];
    const void* ln2b   = d_in[17];
    const void* w1     = d_in[18];
    const void* b1     = d_in[19];
    const void* w2     = d_in[20];
    const void* b2     = d_in[21];
    const void* fng    = d_in[22];
    const void* fnb    = d_in[23];

    const int R = BATCH * NTOK;  // 2048
    char* ws = (char*)d_ws;
    const size_t MB = 1u << 20;
    float* xf   = (float*)(ws);                 // [2048][512] fp32   4 MB
    u16*  yf    = (u16*)(ws + 4 * MB);          // [2048][512] bf16   2 MB
    u16*  of    = (u16*)(ws + 6 * MB);          // [2048][512] bf16   2 MB
    u16*  pool  = (u16*)(ws + 8 * MB);          // 8 MB: ff | qkv | hf
    u16*  ff    = pool;
    u16*  qkvb  = pool;
    u16*  hf    = pool;
    u16*  WeT   = (u16*)(ws + 16 * MB);
    u16*  wqkvT = (u16*)(ws + 16 * MB + 512 * 1024);
    u16*  woT   = (u16*)(ws + 22 * MB + 512 * 1024);
    u16*  w1T   = (u16*)(ws + 24 * MB + 512 * 1024);
    u16*  w2T   = (u16*)(ws + 32 * MB + 512 * 1024);
    float* prm  = (float*)(ws + 40 * MB + 512 * 1024);
    float* cf   = (float*)(ws + 41 * MB);
    float* part = (float*)(ws + 41 * MB + 128 * 1024);
    float* inv_std = (float*)(ws + 41 * MB + 192 * 1024);
    int*   flag = (int*)(ws + 41 * MB + 192 * 1024 + 64);
    // bf16 distance matrix [B*N][N] = 4 MiB at 42 MiB, only if workspace allows
    u16* dist = (ws_size >= (size_t)46 * MB) ? (u16*)(ws + 42 * MB) : nullptr;

    // ---- prep ----
    detect_kernel<<<1, 256, 0, stream>>>(wq, flag);
    cvt_all_kernel<<<(R * DMODEL + 255) / 256, 256, 0, stream>>>(phi, coords, xf, cf, flag);
    pack_params<<<32, 256, 0, stream>>>(be, bq, bk, bv, bo, b1, b2, temp,
                                        ln1g, ln1b, ln2g, ln2b, fng, fnb, modes, prm, flag);
    tr_qkv<<<dim3(16, 16, 12), 256, 0, stream>>>(wq, wk, wv, wqkvT, flag);
    tr_woWe<<<dim3(16, 16, 5), 256, 0, stream>>>(wo, We, woT, WeT, flag);
    tr_gen<<<dim3(64, 16, 4), 256, 0, stream>>>(w1, w1T, 512, 2048, flag);
    tr_gen<<<dim3(16, 64, 4), 256, 0, stream>>>(w2, w2T, 2048, 512, flag);

    // ---- encode ----
    feats_kernel<<<R, 256, 0, stream>>>(cf, prm + OB_MODES, ff);
    gemm_mfma<2, 2, 0, 1, 0><<<dim3(8, 32), 256, 0, stream>>>(ff, WeT, prm + OB_BE, xf, xf,
                                                              R, DMODEL, DMODEL);
    // ---- distances ----
    dstat_kernel<<<R, 256, 0, stream>>>(cf, part, dist);
    dreduce_kernel<<<BATCH, 256, 0, stream>>>(part, inv_std);

    for (int l = 0; l < NLAYER; l++) {
        ln_bf_kernel<<<R, 256, 0, stream>>>(xf, prm + OB_L1G + l * 512, prm + OB_L1B + l * 512, yf);
        gemm_mfma<2, 4, 0, 0, 1><<<dim3(12, 32), 256, 0, stream>>>(
            yf, wqkvT + (size_t)l * 1536 * 512, prm + OB_BQKV + l * 1536, nullptr, qkvb,
            R, 1536, DMODEL);
        if (dist)
            attn_mfma<1><<<dim3(32, NHEAD, BATCH), 256, 0, stream>>>(
                qkvb, cf, inv_std, prm + OB_TEMP, l, dist, of);
        else
            attn_mfma<0><<<dim3(32, NHEAD, BATCH), 256, 0, stream>>>(
                qkvb, cf, inv_std, prm + OB_TEMP, l, nullptr, of);
        gemm_mfma<2, 2, 0, 1, 0><<<dim3(8, 32), 256, 0, stream>>>(
            of, woT + (size_t)l * 512 * 512, prm + OB_BO + l * 512, xf, xf, R, DMODEL, DMODEL);
        ln_bf_kernel<<<R, 256, 0, stream>>>(xf, prm + OB_L2G + l * 512, prm + OB_L2B + l * 512, yf);
        gemm_mfma<4, 4, 1, 0, 1><<<dim3(16, 16), 256, 0, stream>>>(
            yf, w1T + (size_t)l * 2048 * 512, prm + OB_B1 + l * 2048, nullptr, hf,
            R, DFFN, DMODEL);
        gemm_mfma<2, 2, 0, 1, 0><<<dim3(8, 32), 256, 0, stream>>>(
            hf, w2T + (size_t)l * 512 * 2048, prm + OB_B2 + l * 512, xf, xf, R, DMODEL, DFFN);
    }
    ln_out_kernel<<<R, 256, 0, stream>>>(xf, prm + OB_FNG, prm + OB_FNB, d_out, flag);
}

// Round 7
// 538.533 us; speedup vs baseline: 15.0677x; 1.1132x over previous
//
#include <hip/hip_runtime.h>
#include <hip/hip_bf16.h>
#include <math.h>

#define BATCH 2
#define NTOK 1024
#define DMODEL 512
#define NHEAD 8
#define DH 64
#define NLAYER 4
#define MMODES 256
#define DFFN 2048

typedef unsigned short u16;
typedef __attribute__((ext_vector_type(4))) float f4;
typedef __attribute__((ext_vector_type(8))) short b8;

__device__ __forceinline__ float bf2f(u16 u) { return __uint_as_float(((unsigned)u) << 16); }
__device__ __forceinline__ u16 f2b(float x) {
    unsigned u = __float_as_uint(x);
    return (u16)((u + 0x7FFF + ((u >> 16) & 1)) >> 16);
}
__device__ __forceinline__ float ldx(const void* p, size_t i, int f32) {
    return f32 ? ((const float*)p)[i] : bf2f(((const u16*)p)[i]);
}
// async global->LDS, 16 B per lane; LDS dest = wave-uniform base + lane*16
__device__ __forceinline__ void async_ld16(const u16* g, u16* l) {
    __builtin_amdgcn_global_load_lds((const __attribute__((address_space(1))) void*)g,
                                     (__attribute__((address_space(3))) void*)l, 16, 0, 0);
}

// ================= dtype probe (verified) =================
__global__ __launch_bounds__(256) void detect_kernel(const void* __restrict__ probe,
                                                     int* __restrict__ flag) {
    const u16* u = (const u16*)probe;
    int big = 0, zer = 0;
    for (int t = threadIdx.x; t < 768; t += 256) {
        u16 w = u[2 * t];
        int e = (w >> 7) & 0xFF;
        if (e >= 137) big++;
        if (w == 0) zer++;
    }
    __shared__ int sb, sz;
    if (threadIdx.x == 0) { sb = 0; sz = 0; }
    __syncthreads();
    atomicAdd(&sb, big);
    atomicAdd(&sz, zer);
    __syncthreads();
    if (threadIdx.x == 0) flag[0] = (sb >= 64 || sz >= 700) ? 1 : 0;
}

// ================= convert phi/coords -> fp32 =================
__global__ __launch_bounds__(256) void cvt_all_kernel(const void* __restrict__ phi,
                                                      const void* __restrict__ coords,
                                                      float* __restrict__ xf,
                                                      float* __restrict__ cf,
                                                      const int* __restrict__ fl) {
    int f = fl[0];
    int i = blockIdx.x * 256 + threadIdx.x;
    if (i < BATCH * NTOK * DMODEL) xf[i] = ldx(phi, i, f);
    if (i < BATCH * NTOK * 3) cf[i] = ldx(coords, i, f);
}

// ================= pack small params to fp32 =================
#define OB_BE 0
#define OB_BQKV 512
#define OB_BO 6656
#define OB_B1 8704
#define OB_B2 16896
#define OB_TEMP 18944
#define OB_L1G 18976
#define OB_L1B 21024
#define OB_L2G 23072
#define OB_L2B 25120
#define OB_FNG 27168
#define OB_FNB 27680
#define OB_MODES 28192
#define OB_TOTAL 28960
__global__ __launch_bounds__(256) void pack_params(
    const void* be_, const void* bq_, const void* bk_, const void* bv_,
    const void* bo_, const void* b1_, const void* b2_, const void* temp_,
    const void* l1g_, const void* l1b_, const void* l2g_, const void* l2b_,
    const void* fng_, const void* fnb_, const void* modes_,
    float* __restrict__ out, const int* __restrict__ fl) {
    int f = fl[0];
    for (int idx = blockIdx.x * 256 + threadIdx.x; idx < OB_TOTAL; idx += gridDim.x * 256) {
        float v;
        int i = idx;
        if (i < 512) v = ldx(be_, i, f);
        else if ((i -= 512) < 6144) {
            int l = i / 1536, r = i - l * 1536;
            v = (r < 512) ? ldx(bq_, (size_t)l * 512 + r, f)
              : (r < 1024) ? ldx(bk_, (size_t)l * 512 + r - 512, f)
              : ldx(bv_, (size_t)l * 512 + r - 1024, f);
        }
        else if ((i -= 6144) < 2048) v = ldx(bo_, i, f);
        else if ((i -= 2048) < 8192) v = ldx(b1_, i, f);
        else if ((i -= 8192) < 2048) v = ldx(b2_, i, f);
        else if ((i -= 2048) < 32)   v = ldx(temp_, i, f);
        else if ((i -= 32) < 2048)   v = ldx(l1g_, i, f);
        else if ((i -= 2048) < 2048) v = ldx(l1b_, i, f);
        else if ((i -= 2048) < 2048) v = ldx(l2g_, i, f);
        else if ((i -= 2048) < 2048) v = ldx(l2b_, i, f);
        else if ((i -= 2048) < 512)  v = ldx(fng_, i, f);
        else if ((i -= 512) < 512)   v = ldx(fnb_, i, f);
        else { i -= 512; v = ldx(modes_, i, f); }
        out[idx] = v;
    }
}

// ================= weight transpose to bf16 W^T =================
__device__ __forceinline__ void tr_body(const void* src, size_t sbase, u16* dst,
                                        size_t dbase, int R, int C, int dstRowOff, int f) {
    __shared__ float t[32][33];
    int c0 = blockIdx.x * 32, r0 = blockIdx.y * 32;
    int tx = threadIdx.x & 31, ty8 = threadIdx.x >> 5;
#pragma unroll
    for (int rr = 0; rr < 4; rr++) {
        int r = r0 + ty8 + rr * 8;
        t[ty8 + rr * 8][tx] = ldx(src, sbase + (size_t)r * C + c0 + tx, f);
    }
    __syncthreads();
#pragma unroll
    for (int rr = 0; rr < 4; rr++) {
        int c = c0 + ty8 + rr * 8;
        dst[dbase + (size_t)(dstRowOff + c) * R + r0 + tx] = f2b(t[tx][ty8 + rr * 8]);
    }
}
__global__ __launch_bounds__(256) void tr_qkv(const void* wq_, const void* wk_,
                                              const void* wv_, u16* dst,
                                              const int* __restrict__ fl) {
    int z = blockIdx.z, l = z / 3, mat = z - l * 3;
    const void* s = (mat == 0) ? wq_ : (mat == 1) ? wk_ : wv_;
    tr_body(s, (size_t)l * 512 * 512, dst, (size_t)l * 1536 * 512, 512, 512, mat * 512, fl[0]);
}
__global__ __launch_bounds__(256) void tr_woWe(const void* wo_, const void* We_,
                                               u16* woT, u16* WeT,
                                               const int* __restrict__ fl) {
    int z = blockIdx.z;
    if (z < 4) tr_body(wo_, (size_t)z * 512 * 512, woT, (size_t)z * 512 * 512, 512, 512, 0, fl[0]);
    else       tr_body(We_, 0, WeT, 0, 512, 512, 0, fl[0]);
}
__global__ __launch_bounds__(256) void tr_gen(const void* src, u16* dst, int R, int C,
                                              const int* __restrict__ fl) {
    int z = blockIdx.z;
    tr_body(src, (size_t)z * R * C, dst, (size_t)z * R * C, R, C, 0, fl[0]);
}

// ================= Fourier features -> bf16 =================
__global__ __launch_bounds__(256) void feats_kernel(const float* __restrict__ cf,
                                                    const float* __restrict__ modesF,
                                                    u16* __restrict__ ff) {
    int row = blockIdx.x, m = threadIdx.x;
    float cx = cf[row * 3 + 0], cy = cf[row * 3 + 1], cz = cf[row * 3 + 2];
    float ph = cx * modesF[m * 3 + 0] + cy * modesF[m * 3 + 1] + cz * modesF[m * 3 + 2];
    ff[(size_t)row * 512 + m] = f2b(cosf(ph));
    ff[(size_t)row * 512 + MMODES + m] = f2b(sinf(ph));
}

// ================= distance stats + optional bf16 dist matrix =================
__global__ __launch_bounds__(256) void dstat_kernel(const float* __restrict__ cf,
                                                    float* __restrict__ part,
                                                    u16* __restrict__ dist) {
    int b = blockIdx.x >> 10, i = blockIdx.x & 1023;
    const float* cb = cf + (size_t)b * NTOK * 3;
    float xi = cb[i * 3], yi = cb[i * 3 + 1], zi = cb[i * 3 + 2];
    float ls = 0.f, ls2 = 0.f;
    for (int j = threadIdx.x; j < NTOK; j += 256) {
        float dx = xi - (cb[j * 3] + 1e-5f);
        float dy = yi - (cb[j * 3 + 1] + 1e-5f);
        float dz = zi - (cb[j * 3 + 2] + 1e-5f);
        float d = sqrtf(dx * dx + dy * dy + dz * dz);
        if (dist) dist[(((size_t)(b * NTOK + i)) << 10) + j] = f2b(d);
        ls += d; ls2 += d * d;
    }
    for (int off = 32; off; off >>= 1) {
        ls += __shfl_down(ls, off);
        ls2 += __shfl_down(ls2, off);
    }
    __shared__ float rs[4], rs2[4];
    int wid = threadIdx.x >> 6;
    if ((threadIdx.x & 63) == 0) { rs[wid] = ls; rs2[wid] = ls2; }
    __syncthreads();
    if (threadIdx.x == 0) {
        part[blockIdx.x] = rs[0] + rs[1] + rs[2] + rs[3];
        part[2048 + blockIdx.x] = rs2[0] + rs2[1] + rs2[2] + rs2[3];
    }
}
__global__ __launch_bounds__(256) void dreduce_kernel(const float* __restrict__ part,
                                                      float* __restrict__ inv_std) {
    int b = blockIdx.x;
    double s = 0.0, s2 = 0.0;
    for (int t = threadIdx.x; t < NTOK; t += 256) {
        s += (double)part[b * NTOK + t];
        s2 += (double)part[2048 + b * NTOK + t];
    }
    for (int off = 32; off; off >>= 1) {
        s += __shfl_down(s, off);
        s2 += __shfl_down(s2, off);
    }
    __shared__ double ds[4], ds2[4];
    int wid = threadIdx.x >> 6;
    if ((threadIdx.x & 63) == 0) { ds[wid] = s; ds2[wid] = s2; }
    __syncthreads();
    if (threadIdx.x == 0) {
        double S = ds[0] + ds[1] + ds[2] + ds[3];
        double S2 = ds2[0] + ds2[1] + ds2[2] + ds2[3];
        double n = (double)NTOK * (double)NTOK;
        double mean = S / n;
        double var = (S2 - n * mean * mean) / (n - 1.0);
        inv_std[b] = (float)(1.0 / sqrt(var));
    }
}

// ================= LayerNorm: fp32 in -> bf16 out =================
__global__ __launch_bounds__(256) void ln_bf_kernel(const float* __restrict__ x,
                                                    const float* __restrict__ gp,
                                                    const float* __restrict__ bp,
                                                    u16* __restrict__ y) {
    int row = blockIdx.x, tid = threadIdx.x;
    const float* xr = x + (size_t)row * DMODEL;
    float v0 = xr[tid], v1 = xr[tid + 256];
    float s = v0 + v1, s2 = v0 * v0 + v1 * v1;
    for (int off = 32; off; off >>= 1) {
        s += __shfl_down(s, off);
        s2 += __shfl_down(s2, off);
    }
    __shared__ float ls[4], ls2[4];
    int wid = tid >> 6;
    if ((tid & 63) == 0) { ls[wid] = s; ls2[wid] = s2; }
    __syncthreads();
    s = ls[0] + ls[1] + ls[2] + ls[3];
    s2 = ls2[0] + ls2[1] + ls2[2] + ls2[3];
    float mean = s * (1.0f / DMODEL);
    float var = s2 * (1.0f / DMODEL) - mean * mean;
    float r = rsqrtf(var + 1e-5f);
    y[(size_t)row * DMODEL + tid] = f2b((v0 - mean) * r * gp[tid] + bp[tid]);
    y[(size_t)row * DMODEL + tid + 256] = f2b((v1 - mean) * r * gp[tid + 256] + bp[tid + 256]);
}
__global__ __launch_bounds__(256) void ln_out_kernel(const float* __restrict__ x,
                                                     const float* __restrict__ gp,
                                                     const float* __restrict__ bp,
                                                     void* __restrict__ out,
                                                     const int* __restrict__ fl) {
    int f = fl[0];
    int row = blockIdx.x, tid = threadIdx.x;
    const float* xr = x + (size_t)row * DMODEL;
    float v0 = xr[tid], v1 = xr[tid + 256];
    float s = v0 + v1, s2 = v0 * v0 + v1 * v1;
    for (int off = 32; off; off >>= 1) {
        s += __shfl_down(s, off);
        s2 += __shfl_down(s2, off);
    }
    __shared__ float ls[4], ls2[4];
    int wid = tid >> 6;
    if ((tid & 63) == 0) { ls[wid] = s; ls2[wid] = s2; }
    __syncthreads();
    s = ls[0] + ls[1] + ls[2] + ls[3];
    s2 = ls2[0] + ls2[1] + ls2[2] + ls2[3];
    float mean = s * (1.0f / DMODEL);
    float var = s2 * (1.0f / DMODEL) - mean * mean;
    float r = rsqrtf(var + 1e-5f);
    float o0 = (v0 - mean) * r * gp[tid] + bp[tid];
    float o1 = (v1 - mean) * r * gp[tid + 256] + bp[tid + 256];
    size_t i0 = (size_t)row * DMODEL + tid;
    if (f) { ((float*)out)[i0] = o0; ((float*)out)[i0 + 256] = o1; }
    else   { ((u16*)out)[i0] = f2b(o0); ((u16*)out)[i0 + 256] = f2b(o1); }
}

// ================= V transpose per layer: qkv V-part -> VT[b][h][64][1024] =================
__global__ __launch_bounds__(256) void vt_kernel(const u16* __restrict__ qkv,
                                                 u16* __restrict__ VT) {
    const int jc = blockIdx.x, h = blockIdx.y, b = blockIdx.z;
    const int j0 = jc * 64, t = threadIdx.x;
    __shared__ u16 Ls[64][72];
    {
        int j = t >> 2, dc = (t & 3) * 16;
        const u16* vp = qkv + ((size_t)(b * NTOK + j0 + j)) * 1536 + 1024 + h * 64 + dc;
        *(uint4*)&Ls[j][dc] = *(const uint4*)vp;
        *(uint4*)&Ls[j][dc + 8] = *(const uint4*)(vp + 8);
    }
    __syncthreads();
    {
        int d = t >> 2, jc2 = (t & 3) * 16;
        u16 tmp[16];
#pragma unroll
        for (int e = 0; e < 16; e++) tmp[e] = Ls[jc2 + e][d];
        u16* dst = VT + ((size_t)(b * 8 + h)) * 65536 + (size_t)d * 1024 + j0 + jc2;
        *(uint4*)dst = *(uint4*)&tmp[0];
        *(uint4*)(dst + 8) = *(uint4*)&tmp[8];
    }
}

// ================= MFMA GEMM: BK=64 (two 32-halves per barrier), async staging =================
// BM=32*FM, BN=32*FN. C = [res +] act(A @ BT^T + bias).
template <int FM, int FN, int ACT, int RES, int OUTBF>
__global__ __launch_bounds__(256) void gemm_mfma(const u16* __restrict__ A,
                                                 const u16* __restrict__ BT,
                                                 const float* __restrict__ bias,
                                                 const float* __restrict__ res,
                                                 void* __restrict__ Cp,
                                                 int M, int N, int K) {
    constexpr int BM = 32 * FM, BN = 32 * FN;
    constexpr int PA = BM / 64, PB = BN / 64;
    __shared__ u16 As[2 * BM * 32];
    __shared__ u16 Bs[2 * BN * 32];
    const int m0 = blockIdx.y * BM, n0 = blockIdx.x * BN;
    const int tid = threadIdx.x, lane = tid & 63, wid = tid >> 6;
    const int wm = (wid >> 1) * (16 * FM), wn = (wid & 1) * (16 * FN);
    const int quad = lane >> 4, low = lane & 15;
    const int srow = tid >> 2, scol = (tid & 3) * 8;
    f4 acc[FM][FN] = {};
    for (int k0 = 0; k0 < K; k0 += 64) {
#pragma unroll
        for (int ks = 0; ks < 2; ks++) {
#pragma unroll
            for (int p = 0; p < PA; p++)
                async_ld16(A + (size_t)(m0 + p * 64 + srow) * K + k0 + ks * 32 + scol,
                           As + ks * BM * 32 + p * 2048 + wid * 512);
#pragma unroll
            for (int p = 0; p < PB; p++)
                async_ld16(BT + (size_t)(n0 + p * 64 + srow) * K + k0 + ks * 32 + scol,
                           Bs + ks * BN * 32 + p * 2048 + wid * 512);
        }
        __syncthreads();
#pragma unroll
        for (int ks = 0; ks < 2; ks++) {
            b8 af[FM], bfr[FN];
#pragma unroll
            for (int i = 0; i < FM; i++)
                af[i] = *(const b8*)(As + ks * BM * 32 + (wm + i * 16 + low) * 32 + quad * 8);
#pragma unroll
            for (int j = 0; j < FN; j++)
                bfr[j] = *(const b8*)(Bs + ks * BN * 32 + (wn + j * 16 + low) * 32 + quad * 8);
#pragma unroll
            for (int i = 0; i < FM; i++)
#pragma unroll
                for (int j = 0; j < FN; j++)
                    acc[i][j] = __builtin_amdgcn_mfma_f32_16x16x32_bf16(af[i], bfr[j], acc[i][j], 0, 0, 0);
        }
        __syncthreads();
    }
#pragma unroll
    for (int i = 0; i < FM; i++) {
#pragma unroll
        for (int j = 0; j < FN; j++) {
            int gn = n0 + wn + j * 16 + low;
            float bv = bias[gn];
#pragma unroll
            for (int r = 0; r < 4; r++) {
                int gm = m0 + wm + i * 16 + quad * 4 + r;
                float v = acc[i][j][r] + bv;
                if (ACT) v = 0.5f * v * (1.0f + erff(v * 0.70710678f));
                if (RES) v += res[(size_t)gm * N + gn];
                if (OUTBF) ((u16*)Cp)[(size_t)gm * N + gn] = f2b(v);
                else       ((float*)Cp)[(size_t)gm * N + gn] = v;
            }
        }
    }
}

// ================= MFMA flash attention (V from pre-transposed VT) =================
// block = (32-row i-tile, h, b); 4 waves: group g=wid>>1 (16 rows), parity p=wid&1.
template <int USE_DIST>
__global__ __launch_bounds__(256) void attn_mfma(const u16* __restrict__ qkv,  // [R][1536]
                                                 const u16* __restrict__ VT,   // [B*H][64][1024]
                                                 const float* __restrict__ cf,
                                                 const float* __restrict__ inv_std,
                                                 const float* __restrict__ tempF, int l,
                                                 const u16* __restrict__ dist,
                                                 u16* __restrict__ o) {        // [R][512]
    const int it = blockIdx.x, h = blockIdx.y, b = blockIdx.z;
    const int i0 = it * 32, tid = threadIdx.x;
    const int lane = tid & 63, wid = tid >> 6;
    const int g = wid >> 1, p = wid & 1;
    const int quad = lane >> 4, low = lane & 15;
    __shared__ u16 Ks[2][64][72];
    __shared__ u16 Vs[2][64][72];
    __shared__ u16 Ps[4][16][72];
    __shared__ float s_ci[32][3];
    __shared__ float s_cj[2][64][3];
    const size_t rbase = (size_t)b * NTOK;
    const u16* VTh = VT + ((size_t)(b * 8 + h)) * 65536;
    b8 qf0, qf1;
    {
        const u16* qp = qkv + (rbase + i0 + g * 16 + low) * 1536 + h * 64;
        qf0 = *(const b8*)(qp + quad * 8);
        qf1 = *(const b8*)(qp + 32 + quad * 8);
    }
    if (!USE_DIST && tid < 32) {
        s_ci[tid][0] = cf[(rbase + i0 + tid) * 3 + 0];
        s_ci[tid][1] = cf[(rbase + i0 + tid) * 3 + 1];
        s_ci[tid][2] = cf[(rbase + i0 + tid) * 3 + 2];
    }
    float t0 = tempF[l * 8 + h];
    float spw = (fmaxf(t0, 0.f) + log1pf(__expf(-fabsf(t0)))) * inv_std[b];
    float mold[4] = {-1e30f, -1e30f, -1e30f, -1e30f};
    float lsum[4] = {0.f, 0.f, 0.f, 0.f};
    f4 oacc[4] = {};
    __syncthreads();
    float cqx[4], cqy[4], cqz[4];
    const u16* drow[4];
#pragma unroll
    for (int r = 0; r < 4; r++) {
        int ii = g * 16 + quad * 4 + r;
        if (USE_DIST) drow[r] = dist + ((rbase + i0 + ii) << 10);
        else { cqx[r] = s_ci[ii][0]; cqy[r] = s_ci[ii][1]; cqz[r] = s_ci[ii][2]; }
    }
    for (int t = 0; t < 8; t++) {
        __syncthreads();
#pragma unroll
        for (int tt = 0; tt < 2; tt++) {   // stage both parity tiles (K natural, V from VT)
            int j0s = (t * 2 + tt) * 64;
            int j = tid >> 2, dc = (tid & 3) * 16;
            const u16* kp = qkv + (rbase + j0s + j) * 1536 + 512 + h * 64 + dc;
            *(uint4*)&Ks[tt][j][dc] = *(const uint4*)kp;
            *(uint4*)&Ks[tt][j][dc + 8] = *(const uint4*)(kp + 8);
            const u16* vp = VTh + (size_t)j * 1024 + j0s + dc;   // j here = d-row of VT
            *(uint4*)&Vs[tt][j][dc] = *(const uint4*)vp;
            *(uint4*)&Vs[tt][j][dc + 8] = *(const uint4*)(vp + 8);
            if (!USE_DIST && tid < 64) {
                s_cj[tt][tid][0] = cf[(rbase + j0s + tid) * 3 + 0] + 1e-5f;
                s_cj[tt][tid][1] = cf[(rbase + j0s + tid) * 3 + 1] + 1e-5f;
                s_cj[tt][tid][2] = cf[(rbase + j0s + tid) * 3 + 2] + 1e-5f;
            }
        }
        __syncthreads();
        const int j0 = (t * 2 + p) * 64;
        f4 sacc[4] = {};
#pragma unroll
        for (int jb = 0; jb < 4; jb++) {
            b8 bk0 = *(const b8*)&Ks[p][jb * 16 + low][quad * 8];
            b8 bk1 = *(const b8*)&Ks[p][jb * 16 + low][32 + quad * 8];
            sacc[jb] = __builtin_amdgcn_mfma_f32_16x16x32_bf16(qf0, bk0, sacc[jb], 0, 0, 0);
            sacc[jb] = __builtin_amdgcn_mfma_f32_16x16x32_bf16(qf1, bk1, sacc[jb], 0, 0, 0);
        }
        float sv[4][4];
#pragma unroll
        for (int jb = 0; jb < 4; jb++) {
            int j = jb * 16 + low;
            if (USE_DIST) {
#pragma unroll
                for (int r = 0; r < 4; r++)
                    sv[jb][r] = sacc[jb][r] * 0.125f - spw * bf2f(drow[r][j0 + j]);
            } else {
                float cjx = s_cj[p][j][0], cjy = s_cj[p][j][1], cjz = s_cj[p][j][2];
#pragma unroll
                for (int r = 0; r < 4; r++) {
                    float dx = cqx[r] - cjx, dy = cqy[r] - cjy, dz = cqz[r] - cjz;
                    sv[jb][r] = sacc[jb][r] * 0.125f - spw * sqrtf(dx * dx + dy * dy + dz * dz);
                }
            }
        }
        float alpha[4];
#pragma unroll
        for (int r = 0; r < 4; r++) {
            float mx = fmaxf(fmaxf(sv[0][r], sv[1][r]), fmaxf(sv[2][r], sv[3][r]));
            mx = fmaxf(mx, __shfl_xor(mx, 1));
            mx = fmaxf(mx, __shfl_xor(mx, 2));
            mx = fmaxf(mx, __shfl_xor(mx, 4));
            mx = fmaxf(mx, __shfl_xor(mx, 8));
            float mn = fmaxf(mold[r], mx);
            alpha[r] = __expf(mold[r] - mn);
            mold[r] = mn;
            float ps = 0.f;
#pragma unroll
            for (int jb = 0; jb < 4; jb++) {
                float pp = __expf(sv[jb][r] - mn);
                Ps[wid][quad * 4 + r][jb * 16 + low] = f2b(pp);
                ps += pp;
            }
            ps += __shfl_xor(ps, 1);
            ps += __shfl_xor(ps, 2);
            ps += __shfl_xor(ps, 4);
            ps += __shfl_xor(ps, 8);
            lsum[r] = lsum[r] * alpha[r] + ps;
        }
#pragma unroll
        for (int db = 0; db < 4; db++)
#pragma unroll
            for (int r = 0; r < 4; r++) oacc[db][r] *= alpha[r];
        b8 ap0 = *(const b8*)&Ps[wid][low][quad * 8];
        b8 ap1 = *(const b8*)&Ps[wid][low][32 + quad * 8];
#pragma unroll
        for (int db = 0; db < 4; db++) {
            b8 bv0 = *(const b8*)&Vs[p][db * 16 + low][quad * 8];
            b8 bv1 = *(const b8*)&Vs[p][db * 16 + low][32 + quad * 8];
            oacc[db] = __builtin_amdgcn_mfma_f32_16x16x32_bf16(ap0, bv0, oacc[db], 0, 0, 0);
            oacc[db] = __builtin_amdgcn_mfma_f32_16x16x32_bf16(ap1, bv1, oacc[db], 0, 0, 0);
        }
    }
    // ---- merge parity partials (flash-decoding style) ----
    __syncthreads();
    float* scr = (float*)&Ks[0][0][0];   // per group: 1024 O floats + 16 m + 16 l
    float* Og = scr + g * 1088;
    float* Ml = Og + 1024;
    if (p == 1) {
#pragma unroll
        for (int db = 0; db < 4; db++)
#pragma unroll
            for (int r = 0; r < 4; r++)
                Og[(quad * 4 + r) * 64 + db * 16 + low] = oacc[db][r];
        if (low == 0) {
#pragma unroll
            for (int r = 0; r < 4; r++) {
                Ml[quad * 4 + r] = mold[r];
                Ml[16 + quad * 4 + r] = lsum[r];
            }
        }
    }
    __syncthreads();
    if (p == 0) {
#pragma unroll
        for (int r = 0; r < 4; r++) {
            int row = quad * 4 + r;
            float m1 = Ml[row], l1 = Ml[16 + row];
            float mm = fmaxf(mold[r], m1);
            float a0 = __expf(mold[r] - mm), a1 = __expf(m1 - mm);
            float rl = 1.f / (lsum[r] * a0 + l1 * a1);
            u16* op = o + (rbase + i0 + g * 16 + row) * 512 + h * 64 + low;
#pragma unroll
            for (int db = 0; db < 4; db++) {
                float v = oacc[db][r] * a0 + Og[row * 64 + db * 16 + low] * a1;
                op[db * 16] = f2b(v * rl);
            }
        }
    }
}

extern "C" void kernel_launch(void* const* d_in, const int* in_sizes, int n_in,
                              void* d_out, int out_size, void* d_ws, size_t ws_size,
                              hipStream_t stream) {
    const void* phi    = d_in[0];
    const void* coords = d_in[1];
    const void* modes  = d_in[2];
    const void* We     = d_in[3];
    const void* be     = d_in[4];
    const void* wq     = d_in[5];
    const void* bq     = d_in[6];
    const void* wk     = d_in[7];
    const void* bk     = d_in[8];
    const void* wv     = d_in[9];
    const void* bv     = d_in[10];
    const void* wo     = d_in[11];
    const void* bo     = d_in[12];
    const void* temp   = d_in[13];
    const void* ln1g   = d_in[14];
    const void* ln1b   = d_in[15];
    const void* ln2g   = d_in[16];
    const void* ln2b   = d_in[17];
    const void* w1     = d_in[18];
    const void* b1     = d_in[19];
    const void* w2     = d_in[20];
    const void* b2     = d_in[21];
    const void* fng    = d_in[22];
    const void* fnb    = d_in[23];

    const int R = BATCH * NTOK;  // 2048
    char* ws = (char*)d_ws;
    const size_t MB = 1u << 20;
    float* xf   = (float*)(ws);                 // [2048][512] fp32   4 MB
    u16*  yf    = (u16*)(ws + 4 * MB);          // [2048][512] bf16   2 MB
    u16*  of    = (u16*)(ws + 6 * MB);          // [2048][512] bf16   2 MB
    u16*  pool  = (u16*)(ws + 8 * MB);          // 8 MB: ff | qkv+VT | hf
    u16*  ff    = pool;
    u16*  qkvb  = pool;                         // [2048][1536] = 6 MB
    u16*  VTb   = (u16*)(ws + 14 * MB);         // [2][8][64][1024] = 2 MB (after qkvb)
    u16*  hf    = pool;                         // [2048][2048] = 8 MB (FFN, after attn)
    u16*  WeT   = (u16*)(ws + 16 * MB);
    u16*  wqkvT = (u16*)(ws + 16 * MB + 512 * 1024);
    u16*  woT   = (u16*)(ws + 22 * MB + 512 * 1024);
    u16*  w1T   = (u16*)(ws + 24 * MB + 512 * 1024);
    u16*  w2T   = (u16*)(ws + 32 * MB + 512 * 1024);
    float* prm  = (float*)(ws + 40 * MB + 512 * 1024);
    float* cf   = (float*)(ws + 41 * MB);
    float* part = (float*)(ws + 41 * MB + 128 * 1024);
    float* inv_std = (float*)(ws + 41 * MB + 192 * 1024);
    int*   flag = (int*)(ws + 41 * MB + 192 * 1024 + 64);
    u16* dist = (ws_size >= (size_t)46 * MB) ? (u16*)(ws + 42 * MB) : nullptr;

    // ---- prep ----
    detect_kernel<<<1, 256, 0, stream>>>(wq, flag);
    cvt_all_kernel<<<(R * DMODEL + 255) / 256, 256, 0, stream>>>(phi, coords, xf, cf, flag);
    pack_params<<<32, 256, 0, stream>>>(be, bq, bk, bv, bo, b1, b2, temp,
                                        ln1g, ln1b, ln2g, ln2b, fng, fnb, modes, prm, flag);
    tr_qkv<<<dim3(16, 16, 12), 256, 0, stream>>>(wq, wk, wv, wqkvT, flag);
    tr_woWe<<<dim3(16, 16, 5), 256, 0, stream>>>(wo, We, woT, WeT, flag);
    tr_gen<<<dim3(64, 16, 4), 256, 0, stream>>>(w1, w1T, 512, 2048, flag);
    tr_gen<<<dim3(16, 64, 4), 256, 0, stream>>>(w2, w2T, 2048, 512, flag);

    // ---- encode ----
    feats_kernel<<<R, 256, 0, stream>>>(cf, prm + OB_MODES, ff);
    gemm_mfma<2, 2, 0, 1, 0><<<dim3(8, 32), 256, 0, stream>>>(ff, WeT, prm + OB_BE, xf, xf,
                                                              R, DMODEL, DMODEL);
    // ---- distances ----
    dstat_kernel<<<R, 256, 0, stream>>>(cf, part, dist);
    dreduce_kernel<<<BATCH, 256, 0, stream>>>(part, inv_std);

    for (int l = 0; l < NLAYER; l++) {
        ln_bf_kernel<<<R, 256, 0, stream>>>(xf, prm + OB_L1G + l * 512, prm + OB_L1B + l * 512, yf);
        gemm_mfma<2, 2, 0, 0, 1><<<dim3(24, 32), 256, 0, stream>>>(
            yf, wqkvT + (size_t)l * 1536 * 512, prm + OB_BQKV + l * 1536, nullptr, qkvb,
            R, 1536, DMODEL);
        vt_kernel<<<dim3(16, NHEAD, BATCH), 256, 0, stream>>>(qkvb, VTb);
        if (dist)
            attn_mfma<1><<<dim3(32, NHEAD, BATCH), 256, 0, stream>>>(
                qkvb, VTb, cf, inv_std, prm + OB_TEMP, l, dist, of);
        else
            attn_mfma<0><<<dim3(32, NHEAD, BATCH), 256, 0, stream>>>(
                qkvb, VTb, cf, inv_std, prm + OB_TEMP, l, nullptr, of);
        gemm_mfma<2, 2, 0, 1, 0><<<dim3(8, 32), 256, 0, stream>>>(
            of, woT + (size_t)l * 512 * 512, prm + OB_BO + l * 512, xf, xf, R, DMODEL, DMODEL);
        ln_bf_kernel<<<R, 256, 0, stream>>>(xf, prm + OB_L2G + l * 512, prm + OB_L2B + l * 512, yf);
        gemm_mfma<4, 2, 1, 0, 1><<<dim3(32, 16), 256, 0, stream>>>(
            yf, w1T + (size_t)l * 2048 * 512, prm + OB_B1 + l * 2048, nullptr, hf,
            R, DFFN, DMODEL);
        gemm_mfma<2, 2, 0, 1, 0><<<dim3(8, 32), 256, 0, stream>>>(
            hf, w2T + (size_t)l * 512 * 2048, prm + OB_B2 + l * 512, xf, xf, R, DMODEL, DFFN);
    }
    ln_out_kernel<<<R, 256, 0, stream>>>(xf, prm + OB_FNG, prm + OB_FNB, d_out, flag);
}

// Round 8
// 517.650 us; speedup vs baseline: 15.6756x; 1.0403x over previous
//
#include <hip/hip_runtime.h>
#include <hip/hip_bf16.h>
#include <math.h>

#define BATCH 2
#define NTOK 1024
#define DMODEL 512
#define NHEAD 8
#define DH 64
#define NLAYER 4
#define MMODES 256
#define DFFN 2048

typedef unsigned short u16;
typedef __attribute__((ext_vector_type(4))) float f4;
typedef __attribute__((ext_vector_type(8))) short b8;

__device__ __forceinline__ float bf2f(u16 u) { return __uint_as_float(((unsigned)u) << 16); }
__device__ __forceinline__ u16 f2b(float x) {
    unsigned u = __float_as_uint(x);
    return (u16)((u + 0x7FFF + ((u >> 16) & 1)) >> 16);
}
__device__ __forceinline__ float ldx(const void* p, size_t i, int f32) {
    return f32 ? ((const float*)p)[i] : bf2f(((const u16*)p)[i]);
}
// async global->LDS, 16 B per lane; LDS dest = wave-uniform base + lane*16
__device__ __forceinline__ void async_ld16(const u16* g, u16* l) {
    __builtin_amdgcn_global_load_lds((const __attribute__((address_space(1))) void*)g,
                                     (__attribute__((address_space(3))) void*)l, 16, 0, 0);
}

// ================= dtype probe (verified) =================
__global__ __launch_bounds__(256) void detect_kernel(const void* __restrict__ probe,
                                                     int* __restrict__ flag) {
    const u16* u = (const u16*)probe;
    int big = 0, zer = 0;
    for (int t = threadIdx.x; t < 768; t += 256) {
        u16 w = u[2 * t];
        int e = (w >> 7) & 0xFF;
        if (e >= 137) big++;
        if (w == 0) zer++;
    }
    __shared__ int sb, sz;
    if (threadIdx.x == 0) { sb = 0; sz = 0; }
    __syncthreads();
    atomicAdd(&sb, big);
    atomicAdd(&sz, zer);
    __syncthreads();
    if (threadIdx.x == 0) flag[0] = (sb >= 64 || sz >= 700) ? 1 : 0;
}

// ================= convert phi/coords -> fp32 =================
__global__ __launch_bounds__(256) void cvt_all_kernel(const void* __restrict__ phi,
                                                      const void* __restrict__ coords,
                                                      float* __restrict__ xf,
                                                      float* __restrict__ cf,
                                                      const int* __restrict__ fl) {
    int f = fl[0];
    int i = blockIdx.x * 256 + threadIdx.x;
    if (i < BATCH * NTOK * DMODEL) xf[i] = ldx(phi, i, f);
    if (i < BATCH * NTOK * 3) cf[i] = ldx(coords, i, f);
}

// ================= pack small params to fp32 =================
#define OB_BE 0
#define OB_BQKV 512
#define OB_BO 6656
#define OB_B1 8704
#define OB_B2 16896
#define OB_TEMP 18944
#define OB_L1G 18976
#define OB_L1B 21024
#define OB_L2G 23072
#define OB_L2B 25120
#define OB_FNG 27168
#define OB_FNB 27680
#define OB_MODES 28192
#define OB_TOTAL 28960
__global__ __launch_bounds__(256) void pack_params(
    const void* be_, const void* bq_, const void* bk_, const void* bv_,
    const void* bo_, const void* b1_, const void* b2_, const void* temp_,
    const void* l1g_, const void* l1b_, const void* l2g_, const void* l2b_,
    const void* fng_, const void* fnb_, const void* modes_,
    float* __restrict__ out, const int* __restrict__ fl) {
    int f = fl[0];
    for (int idx = blockIdx.x * 256 + threadIdx.x; idx < OB_TOTAL; idx += gridDim.x * 256) {
        float v;
        int i = idx;
        if (i < 512) v = ldx(be_, i, f);
        else if ((i -= 512) < 6144) {
            int l = i / 1536, r = i - l * 1536;
            v = (r < 512) ? ldx(bq_, (size_t)l * 512 + r, f)
              : (r < 1024) ? ldx(bk_, (size_t)l * 512 + r - 512, f)
              : ldx(bv_, (size_t)l * 512 + r - 1024, f);
        }
        else if ((i -= 6144) < 2048) v = ldx(bo_, i, f);
        else if ((i -= 2048) < 8192) v = ldx(b1_, i, f);
        else if ((i -= 8192) < 2048) v = ldx(b2_, i, f);
        else if ((i -= 2048) < 32)   v = ldx(temp_, i, f);
        else if ((i -= 32) < 2048)   v = ldx(l1g_, i, f);
        else if ((i -= 2048) < 2048) v = ldx(l1b_, i, f);
        else if ((i -= 2048) < 2048) v = ldx(l2g_, i, f);
        else if ((i -= 2048) < 2048) v = ldx(l2b_, i, f);
        else if ((i -= 2048) < 512)  v = ldx(fng_, i, f);
        else if ((i -= 512) < 512)   v = ldx(fnb_, i, f);
        else { i -= 512; v = ldx(modes_, i, f); }
        out[idx] = v;
    }
}

// ================= weight transpose: ONE kernel, all 25 matrices =================
__device__ __forceinline__ void tr_tile(const void* src, size_t sbase, u16* dst,
                                        size_t dbase, int R, int C, int dstRowOff,
                                        int c0, int r0, int f) {
    __shared__ float t[32][33];
    int tx = threadIdx.x & 31, ty8 = threadIdx.x >> 5;
#pragma unroll
    for (int rr = 0; rr < 4; rr++) {
        int r = r0 + ty8 + rr * 8;
        t[ty8 + rr * 8][tx] = ldx(src, sbase + (size_t)r * C + c0 + tx, f);
    }
    __syncthreads();
#pragma unroll
    for (int rr = 0; rr < 4; rr++) {
        int c = c0 + ty8 + rr * 8;
        dst[dbase + (size_t)(dstRowOff + c) * R + r0 + tx] = f2b(t[tx][ty8 + rr * 8]);
    }
}
// tiles: qkv 3072 | wo 1024 | We 256 | w1 4096 | w2 4096  => 12544 blocks
__global__ __launch_bounds__(256) void tr_all(const void* wq_, const void* wk_, const void* wv_,
                                              const void* wo_, const void* We_,
                                              const void* w1_, const void* w2_,
                                              u16* wqkvT, u16* woT, u16* WeT,
                                              u16* w1T, u16* w2T,
                                              const int* __restrict__ fl) {
    int f = fl[0];
    int z = blockIdx.x;
    if (z < 3072) {
        int mat = z >> 8, t = z & 255;
        int l = mat / 3, m3 = mat - l * 3;
        const void* s = (m3 == 0) ? wq_ : (m3 == 1) ? wk_ : wv_;
        tr_tile(s, (size_t)l * 512 * 512, wqkvT, (size_t)l * 1536 * 512,
                512, 512, m3 * 512, (t & 15) * 32, (t >> 4) * 32, f);
    } else if (z < 4096) {
        int zz = z - 3072, l = zz >> 8, t = zz & 255;
        tr_tile(wo_, (size_t)l * 512 * 512, woT, (size_t)l * 512 * 512,
                512, 512, 0, (t & 15) * 32, (t >> 4) * 32, f);
    } else if (z < 4352) {
        int t = z - 4096;
        tr_tile(We_, 0, WeT, 0, 512, 512, 0, (t & 15) * 32, (t >> 4) * 32, f);
    } else if (z < 8448) {
        int zz = z - 4352, l = zz >> 10, t = zz & 1023;
        tr_tile(w1_, (size_t)l * 512 * 2048, w1T, (size_t)l * 2048 * 512,
                512, 2048, 0, (t & 63) * 32, (t >> 6) * 32, f);
    } else {
        int zz = z - 8448, l = zz >> 10, t = zz & 1023;
        tr_tile(w2_, (size_t)l * 2048 * 512, w2T, (size_t)l * 512 * 2048,
                2048, 512, 0, (t & 15) * 32, (t >> 4) * 32, f);
    }
}

// ================= Fourier features + distance stats (merged, same grid) =================
__global__ __launch_bounds__(256) void feats_dstat(const float* __restrict__ cf,
                                                   const float* __restrict__ modesF,
                                                   u16* __restrict__ ff,
                                                   float* __restrict__ part,
                                                   u16* __restrict__ dist) {
    int row = blockIdx.x;            // 0..2047
    {   // Fourier features: m = tid
        int m = threadIdx.x;
        float cx = cf[row * 3 + 0], cy = cf[row * 3 + 1], cz = cf[row * 3 + 2];
        float ph = cx * modesF[m * 3 + 0] + cy * modesF[m * 3 + 1] + cz * modesF[m * 3 + 2];
        ff[(size_t)row * 512 + m] = f2b(cosf(ph));
        ff[(size_t)row * 512 + MMODES + m] = f2b(sinf(ph));
    }
    // distance stats + bf16 dist row
    int b = row >> 10, i = row & 1023;
    const float* cb = cf + (size_t)b * NTOK * 3;
    float xi = cb[i * 3], yi = cb[i * 3 + 1], zi = cb[i * 3 + 2];
    float ls = 0.f, ls2 = 0.f;
    for (int j = threadIdx.x; j < NTOK; j += 256) {
        float dx = xi - (cb[j * 3] + 1e-5f);
        float dy = yi - (cb[j * 3 + 1] + 1e-5f);
        float dz = zi - (cb[j * 3 + 2] + 1e-5f);
        float d = sqrtf(dx * dx + dy * dy + dz * dz);
        if (dist) dist[(((size_t)row) << 10) + j] = f2b(d);
        ls += d; ls2 += d * d;
    }
    for (int off = 32; off; off >>= 1) {
        ls += __shfl_down(ls, off);
        ls2 += __shfl_down(ls2, off);
    }
    __shared__ float rs[4], rs2[4];
    int wid = threadIdx.x >> 6;
    if ((threadIdx.x & 63) == 0) { rs[wid] = ls; rs2[wid] = ls2; }
    __syncthreads();
    if (threadIdx.x == 0) {
        part[row] = rs[0] + rs[1] + rs[2] + rs[3];
        part[2048 + row] = rs2[0] + rs2[1] + rs2[2] + rs2[3];
    }
}
__global__ __launch_bounds__(256) void dreduce_kernel(const float* __restrict__ part,
                                                      float* __restrict__ inv_std) {
    int b = blockIdx.x;
    double s = 0.0, s2 = 0.0;
    for (int t = threadIdx.x; t < NTOK; t += 256) {
        s += (double)part[b * NTOK + t];
        s2 += (double)part[2048 + b * NTOK + t];
    }
    for (int off = 32; off; off >>= 1) {
        s += __shfl_down(s, off);
        s2 += __shfl_down(s2, off);
    }
    __shared__ double ds[4], ds2[4];
    int wid = threadIdx.x >> 6;
    if ((threadIdx.x & 63) == 0) { ds[wid] = s; ds2[wid] = s2; }
    __syncthreads();
    if (threadIdx.x == 0) {
        double S = ds[0] + ds[1] + ds[2] + ds[3];
        double S2 = ds2[0] + ds2[1] + ds2[2] + ds2[3];
        double n = (double)NTOK * (double)NTOK;
        double mean = S / n;
        double var = (S2 - n * mean * mean) / (n - 1.0);
        inv_std[b] = (float)(1.0 / sqrt(var));
    }
}

// ================= LayerNorm: fp32 in -> bf16 out =================
__global__ __launch_bounds__(256) void ln_bf_kernel(const float* __restrict__ x,
                                                    const float* __restrict__ gp,
                                                    const float* __restrict__ bp,
                                                    u16* __restrict__ y) {
    int row = blockIdx.x, tid = threadIdx.x;
    const float* xr = x + (size_t)row * DMODEL;
    float v0 = xr[tid], v1 = xr[tid + 256];
    float s = v0 + v1, s2 = v0 * v0 + v1 * v1;
    for (int off = 32; off; off >>= 1) {
        s += __shfl_down(s, off);
        s2 += __shfl_down(s2, off);
    }
    __shared__ float ls[4], ls2[4];
    int wid = tid >> 6;
    if ((tid & 63) == 0) { ls[wid] = s; ls2[wid] = s2; }
    __syncthreads();
    s = ls[0] + ls[1] + ls[2] + ls[3];
    s2 = ls2[0] + ls2[1] + ls2[2] + ls2[3];
    float mean = s * (1.0f / DMODEL);
    float var = s2 * (1.0f / DMODEL) - mean * mean;
    float r = rsqrtf(var + 1e-5f);
    y[(size_t)row * DMODEL + tid] = f2b((v0 - mean) * r * gp[tid] + bp[tid]);
    y[(size_t)row * DMODEL + tid + 256] = f2b((v1 - mean) * r * gp[tid + 256] + bp[tid + 256]);
}
__global__ __launch_bounds__(256) void ln_out_kernel(const float* __restrict__ x,
                                                     const float* __restrict__ gp,
                                                     const float* __restrict__ bp,
                                                     void* __restrict__ out,
                                                     const int* __restrict__ fl) {
    int f = fl[0];
    int row = blockIdx.x, tid = threadIdx.x;
    const float* xr = x + (size_t)row * DMODEL;
    float v0 = xr[tid], v1 = xr[tid + 256];
    float s = v0 + v1, s2 = v0 * v0 + v1 * v1;
    for (int off = 32; off; off >>= 1) {
        s += __shfl_down(s, off);
        s2 += __shfl_down(s2, off);
    }
    __shared__ float ls[4], ls2[4];
    int wid = tid >> 6;
    if ((tid & 63) == 0) { ls[wid] = s; ls2[wid] = s2; }
    __syncthreads();
    s = ls[0] + ls[1] + ls[2] + ls[3];
    s2 = ls2[0] + ls2[1] + ls2[2] + ls2[3];
    float mean = s * (1.0f / DMODEL);
    float var = s2 * (1.0f / DMODEL) - mean * mean;
    float r = rsqrtf(var + 1e-5f);
    float o0 = (v0 - mean) * r * gp[tid] + bp[tid];
    float o1 = (v1 - mean) * r * gp[tid + 256] + bp[tid + 256];
    size_t i0 = (size_t)row * DMODEL + tid;
    if (f) { ((float*)out)[i0] = o0; ((float*)out)[i0 + 256] = o1; }
    else   { ((u16*)out)[i0] = f2b(o0); ((u16*)out)[i0 + 256] = f2b(o1); }
}

// ================= MFMA GEMM: BK=64, async staging; QKV mode writes V into VT =================
// BM=32*FM, BN=32*FN. C = [res +] act(A @ BT^T + bias).
template <int FM, int FN, int ACT, int RES, int OUTBF, int QKV>
__global__ __launch_bounds__(256) void gemm_mfma(const u16* __restrict__ A,
                                                 const u16* __restrict__ BT,
                                                 const float* __restrict__ bias,
                                                 const float* __restrict__ res,
                                                 void* __restrict__ Cp,
                                                 u16* __restrict__ VTp,
                                                 int M, int N, int K) {
    constexpr int BM = 32 * FM, BN = 32 * FN;
    constexpr int PA = BM / 64, PB = BN / 64;
    __shared__ u16 As[2 * BM * 32];
    __shared__ u16 Bs[2 * BN * 32];
    const int m0 = blockIdx.y * BM, n0 = blockIdx.x * BN;
    const int tid = threadIdx.x, lane = tid & 63, wid = tid >> 6;
    const int wm = (wid >> 1) * (16 * FM), wn = (wid & 1) * (16 * FN);
    const int quad = lane >> 4, low = lane & 15;
    const int srow = tid >> 2, scol = (tid & 3) * 8;
    f4 acc[FM][FN] = {};
    for (int k0 = 0; k0 < K; k0 += 64) {
#pragma unroll
        for (int ks = 0; ks < 2; ks++) {
#pragma unroll
            for (int p = 0; p < PA; p++)
                async_ld16(A + (size_t)(m0 + p * 64 + srow) * K + k0 + ks * 32 + scol,
                           As + ks * BM * 32 + p * 2048 + wid * 512);
#pragma unroll
            for (int p = 0; p < PB; p++)
                async_ld16(BT + (size_t)(n0 + p * 64 + srow) * K + k0 + ks * 32 + scol,
                           Bs + ks * BN * 32 + p * 2048 + wid * 512);
        }
        __syncthreads();
#pragma unroll
        for (int ks = 0; ks < 2; ks++) {
            b8 af[FM], bfr[FN];
#pragma unroll
            for (int i = 0; i < FM; i++)
                af[i] = *(const b8*)(As + ks * BM * 32 + (wm + i * 16 + low) * 32 + quad * 8);
#pragma unroll
            for (int j = 0; j < FN; j++)
                bfr[j] = *(const b8*)(Bs + ks * BN * 32 + (wn + j * 16 + low) * 32 + quad * 8);
#pragma unroll
            for (int i = 0; i < FM; i++)
#pragma unroll
                for (int j = 0; j < FN; j++)
                    acc[i][j] = __builtin_amdgcn_mfma_f32_16x16x32_bf16(af[i], bfr[j], acc[i][j], 0, 0, 0);
        }
        __syncthreads();
    }
#pragma unroll
    for (int i = 0; i < FM; i++) {
#pragma unroll
        for (int j = 0; j < FN; j++) {
            int gn = n0 + wn + j * 16 + low;
            float bv = bias[gn];
            if (QKV && gn >= 1024) {
                // V output -> VT[b][h][d][j]: 4 consecutive j per lane = one 8B store
                int h = (gn - 1024) >> 6, d = (gn - 1024) & 63;
                int gmb = m0 + wm + i * 16 + quad * 4;
                int bb = gmb >> 10, jj = gmb & 1023;
                ushort4 pk;
                pk.x = f2b(acc[i][j][0] + bv);
                pk.y = f2b(acc[i][j][1] + bv);
                pk.z = f2b(acc[i][j][2] + bv);
                pk.w = f2b(acc[i][j][3] + bv);
                *(ushort4*)(VTp + ((size_t)(bb * 8 + h) * 64 + d) * 1024 + jj) = pk;
            } else {
#pragma unroll
                for (int r = 0; r < 4; r++) {
                    int gm = m0 + wm + i * 16 + quad * 4 + r;
                    float v = acc[i][j][r] + bv;
                    if (ACT) v = 0.5f * v * (1.0f + erff(v * 0.70710678f));
                    if (RES) v += res[(size_t)gm * N + gn];
                    if (OUTBF) ((u16*)Cp)[(size_t)gm * N + gn] = f2b(v);
                    else       ((float*)Cp)[(size_t)gm * N + gn] = v;
                }
            }
        }
    }
}

// ================= MFMA flash attention (V from pre-transposed VT) =================
// block = (32-row i-tile, h, b); 4 waves: group g=wid>>1 (16 rows), parity p=wid&1.
template <int USE_DIST>
__global__ __launch_bounds__(256) void attn_mfma(const u16* __restrict__ qkv,  // [R][1536] (q,k valid)
                                                 const u16* __restrict__ VT,   // [B*H][64][1024]
                                                 const float* __restrict__ cf,
                                                 const float* __restrict__ inv_std,
                                                 const float* __restrict__ tempF, int l,
                                                 const u16* __restrict__ dist,
                                                 u16* __restrict__ o) {        // [R][512]
    const int it = blockIdx.x, h = blockIdx.y, b = blockIdx.z;
    const int i0 = it * 32, tid = threadIdx.x;
    const int lane = tid & 63, wid = tid >> 6;
    const int g = wid >> 1, p = wid & 1;
    const int quad = lane >> 4, low = lane & 15;
    __shared__ u16 Ks[2][64][72];
    __shared__ u16 Vs[2][64][72];
    __shared__ u16 Ps[4][16][72];
    __shared__ float s_ci[32][3];
    __shared__ float s_cj[2][64][3];
    const size_t rbase = (size_t)b * NTOK;
    const u16* VTh = VT + ((size_t)(b * 8 + h)) * 65536;
    b8 qf0, qf1;
    {
        const u16* qp = qkv + (rbase + i0 + g * 16 + low) * 1536 + h * 64;
        qf0 = *(const b8*)(qp + quad * 8);
        qf1 = *(const b8*)(qp + 32 + quad * 8);
    }
    if (!USE_DIST && tid < 32) {
        s_ci[tid][0] = cf[(rbase + i0 + tid) * 3 + 0];
        s_ci[tid][1] = cf[(rbase + i0 + tid) * 3 + 1];
        s_ci[tid][2] = cf[(rbase + i0 + tid) * 3 + 2];
    }
    float t0 = tempF[l * 8 + h];
    float spw = (fmaxf(t0, 0.f) + log1pf(__expf(-fabsf(t0)))) * inv_std[b];
    float mold[4] = {-1e30f, -1e30f, -1e30f, -1e30f};
    float lsum[4] = {0.f, 0.f, 0.f, 0.f};
    f4 oacc[4] = {};
    __syncthreads();
    float cqx[4], cqy[4], cqz[4];
    const u16* drow[4];
#pragma unroll
    for (int r = 0; r < 4; r++) {
        int ii = g * 16 + quad * 4 + r;
        if (USE_DIST) drow[r] = dist + ((rbase + i0 + ii) << 10);
        else { cqx[r] = s_ci[ii][0]; cqy[r] = s_ci[ii][1]; cqz[r] = s_ci[ii][2]; }
    }
    for (int t = 0; t < 8; t++) {
        __syncthreads();
#pragma unroll
        for (int tt = 0; tt < 2; tt++) {   // stage both parity tiles (K natural, V from VT)
            int j0s = (t * 2 + tt) * 64;
            int j = tid >> 2, dc = (tid & 3) * 16;
            const u16* kp = qkv + (rbase + j0s + j) * 1536 + 512 + h * 64 + dc;
            *(uint4*)&Ks[tt][j][dc] = *(const uint4*)kp;
            *(uint4*)&Ks[tt][j][dc + 8] = *(const uint4*)(kp + 8);
            const u16* vp = VTh + (size_t)j * 1024 + j0s + dc;   // j here = d-row of VT
            *(uint4*)&Vs[tt][j][dc] = *(const uint4*)vp;
            *(uint4*)&Vs[tt][j][dc + 8] = *(const uint4*)(vp + 8);
            if (!USE_DIST && tid < 64) {
                s_cj[tt][tid][0] = cf[(rbase + j0s + tid) * 3 + 0] + 1e-5f;
                s_cj[tt][tid][1] = cf[(rbase + j0s + tid) * 3 + 1] + 1e-5f;
                s_cj[tt][tid][2] = cf[(rbase + j0s + tid) * 3 + 2] + 1e-5f;
            }
        }
        __syncthreads();
        const int j0 = (t * 2 + p) * 64;
        f4 sacc[4] = {};
#pragma unroll
        for (int jb = 0; jb < 4; jb++) {
            b8 bk0 = *(const b8*)&Ks[p][jb * 16 + low][quad * 8];
            b8 bk1 = *(const b8*)&Ks[p][jb * 16 + low][32 + quad * 8];
            sacc[jb] = __builtin_amdgcn_mfma_f32_16x16x32_bf16(qf0, bk0, sacc[jb], 0, 0, 0);
            sacc[jb] = __builtin_amdgcn_mfma_f32_16x16x32_bf16(qf1, bk1, sacc[jb], 0, 0, 0);
        }
        float sv[4][4];
#pragma unroll
        for (int jb = 0; jb < 4; jb++) {
            int j = jb * 16 + low;
            if (USE_DIST) {
#pragma unroll
                for (int r = 0; r < 4; r++)
                    sv[jb][r] = sacc[jb][r] * 0.125f - spw * bf2f(drow[r][j0 + j]);
            } else {
                float cjx = s_cj[p][j][0], cjy = s_cj[p][j][1], cjz = s_cj[p][j][2];
#pragma unroll
                for (int r = 0; r < 4; r++) {
                    float dx = cqx[r] - cjx, dy = cqy[r] - cjy, dz = cqz[r] - cjz;
                    sv[jb][r] = sacc[jb][r] * 0.125f - spw * sqrtf(dx * dx + dy * dy + dz * dz);
                }
            }
        }
        float alpha[4];
#pragma unroll
        for (int r = 0; r < 4; r++) {
            float mx = fmaxf(fmaxf(sv[0][r], sv[1][r]), fmaxf(sv[2][r], sv[3][r]));
            mx = fmaxf(mx, __shfl_xor(mx, 1));
            mx = fmaxf(mx, __shfl_xor(mx, 2));
            mx = fmaxf(mx, __shfl_xor(mx, 4));
            mx = fmaxf(mx, __shfl_xor(mx, 8));
            float mn = fmaxf(mold[r], mx);
            alpha[r] = __expf(mold[r] - mn);
            mold[r] = mn;
            float ps = 0.f;
#pragma unroll
            for (int jb = 0; jb < 4; jb++) {
                float pp = __expf(sv[jb][r] - mn);
                Ps[wid][quad * 4 + r][jb * 16 + low] = f2b(pp);
                ps += pp;
            }
            ps += __shfl_xor(ps, 1);
            ps += __shfl_xor(ps, 2);
            ps += __shfl_xor(ps, 4);
            ps += __shfl_xor(ps, 8);
            lsum[r] = lsum[r] * alpha[r] + ps;
        }
#pragma unroll
        for (int db = 0; db < 4; db++)
#pragma unroll
            for (int r = 0; r < 4; r++) oacc[db][r] *= alpha[r];
        b8 ap0 = *(const b8*)&Ps[wid][low][quad * 8];
        b8 ap1 = *(const b8*)&Ps[wid][low][32 + quad * 8];
#pragma unroll
        for (int db = 0; db < 4; db++) {
            b8 bv0 = *(const b8*)&Vs[p][db * 16 + low][quad * 8];
            b8 bv1 = *(const b8*)&Vs[p][db * 16 + low][32 + quad * 8];
            oacc[db] = __builtin_amdgcn_mfma_f32_16x16x32_bf16(ap0, bv0, oacc[db], 0, 0, 0);
            oacc[db] = __builtin_amdgcn_mfma_f32_16x16x32_bf16(ap1, bv1, oacc[db], 0, 0, 0);
        }
    }
    // ---- merge parity partials (flash-decoding style) ----
    __syncthreads();
    float* scr = (float*)&Ks[0][0][0];   // per group: 1024 O floats + 16 m + 16 l
    float* Og = scr + g * 1088;
    float* Ml = Og + 1024;
    if (p == 1) {
#pragma unroll
        for (int db = 0; db < 4; db++)
#pragma unroll
            for (int r = 0; r < 4; r++)
                Og[(quad * 4 + r) * 64 + db * 16 + low] = oacc[db][r];
        if (low == 0) {
#pragma unroll
            for (int r = 0; r < 4; r++) {
                Ml[quad * 4 + r] = mold[r];
                Ml[16 + quad * 4 + r] = lsum[r];
            }
        }
    }
    __syncthreads();
    if (p == 0) {
#pragma unroll
        for (int r = 0; r < 4; r++) {
            int row = quad * 4 + r;
            float m1 = Ml[row], l1 = Ml[16 + row];
            float mm = fmaxf(mold[r], m1);
            float a0 = __expf(mold[r] - mm), a1 = __expf(m1 - mm);
            float rl = 1.f / (lsum[r] * a0 + l1 * a1);
            u16* op = o + (rbase + i0 + g * 16 + row) * 512 + h * 64 + low;
#pragma unroll
            for (int db = 0; db < 4; db++) {
                float v = oacc[db][r] * a0 + Og[row * 64 + db * 16 + low] * a1;
                op[db * 16] = f2b(v * rl);
            }
        }
    }
}

extern "C" void kernel_launch(void* const* d_in, const int* in_sizes, int n_in,
                              void* d_out, int out_size, void* d_ws, size_t ws_size,
                              hipStream_t stream) {
    const void* phi    = d_in[0];
    const void* coords = d_in[1];
    const void* modes  = d_in[2];
    const void* We     = d_in[3];
    const void* be     = d_in[4];
    const void* wq     = d_in[5];
    const void* bq     = d_in[6];
    const void* wk     = d_in[7];
    const void* bk     = d_in[8];
    const void* wv     = d_in[9];
    const void* bv     = d_in[10];
    const void* wo     = d_in[11];
    const void* bo     = d_in[12];
    const void* temp   = d_in[13];
    const void* ln1g   = d_in[14];
    const void* ln1b   = d_in[15];
    const void* ln2g   = d_in[16];
    const void* ln2b   = d_in[17];
    const void* w1     = d_in[18];
    const void* b1     = d_in[19];
    const void* w2     = d_in[20];
    const void* b2     = d_in[21];
    const void* fng    = d_in[22];
    const void* fnb    = d_in[23];

    const int R = BATCH * NTOK;  // 2048
    char* ws = (char*)d_ws;
    const size_t MB = 1u << 20;
    float* xf   = (float*)(ws);                 // [2048][512] fp32   4 MB
    u16*  yf    = (u16*)(ws + 4 * MB);          // [2048][512] bf16   2 MB
    u16*  of    = (u16*)(ws + 6 * MB);          // [2048][512] bf16   2 MB
    u16*  pool  = (u16*)(ws + 8 * MB);          // 8 MB: ff | qkv+VT | hf
    u16*  ff    = pool;
    u16*  qkvb  = pool;                         // [2048][1536] = 6 MB (q,k valid)
    u16*  VTb   = (u16*)(ws + 14 * MB);         // [2][8][64][1024] = 2 MB
    u16*  hf    = pool;                         // [2048][2048] = 8 MB (FFN)
    u16*  WeT   = (u16*)(ws + 16 * MB);
    u16*  wqkvT = (u16*)(ws + 16 * MB + 512 * 1024);
    u16*  woT   = (u16*)(ws + 22 * MB + 512 * 1024);
    u16*  w1T   = (u16*)(ws + 24 * MB + 512 * 1024);
    u16*  w2T   = (u16*)(ws + 32 * MB + 512 * 1024);
    float* prm  = (float*)(ws + 40 * MB + 512 * 1024);
    float* cf   = (float*)(ws + 41 * MB);
    float* part = (float*)(ws + 41 * MB + 128 * 1024);
    float* inv_std = (float*)(ws + 41 * MB + 192 * 1024);
    int*   flag = (int*)(ws + 41 * MB + 192 * 1024 + 64);
    u16* dist = (ws_size >= (size_t)46 * MB) ? (u16*)(ws + 42 * MB) : nullptr;

    // ---- prep ----
    detect_kernel<<<1, 256, 0, stream>>>(wq, flag);
    cvt_all_kernel<<<(R * DMODEL + 255) / 256, 256, 0, stream>>>(phi, coords, xf, cf, flag);
    pack_params<<<32, 256, 0, stream>>>(be, bq, bk, bv, bo, b1, b2, temp,
                                        ln1g, ln1b, ln2g, ln2b, fng, fnb, modes, prm, flag);
    tr_all<<<12544, 256, 0, stream>>>(wq, wk, wv, wo, We, w1, w2,
                                      wqkvT, woT, WeT, w1T, w2T, flag);

    // ---- encode + distances ----
    feats_dstat<<<R, 256, 0, stream>>>(cf, prm + OB_MODES, ff, part, dist);
    dreduce_kernel<<<BATCH, 256, 0, stream>>>(part, inv_std);
    gemm_mfma<2, 2, 0, 1, 0, 0><<<dim3(8, 32), 256, 0, stream>>>(
        ff, WeT, prm + OB_BE, xf, xf, nullptr, R, DMODEL, DMODEL);

    for (int l = 0; l < NLAYER; l++) {
        ln_bf_kernel<<<R, 256, 0, stream>>>(xf, prm + OB_L1G + l * 512, prm + OB_L1B + l * 512, yf);
        gemm_mfma<2, 2, 0, 0, 1, 1><<<dim3(24, 32), 256, 0, stream>>>(
            yf, wqkvT + (size_t)l * 1536 * 512, prm + OB_BQKV + l * 1536, nullptr, qkvb, VTb,
            R, 1536, DMODEL);
        if (dist)
            attn_mfma<1><<<dim3(32, NHEAD, BATCH), 256, 0, stream>>>(
                qkvb, VTb, cf, inv_std, prm + OB_TEMP, l, dist, of);
        else
            attn_mfma<0><<<dim3(32, NHEAD, BATCH), 256, 0, stream>>>(
                qkvb, VTb, cf, inv_std, prm + OB_TEMP, l, nullptr, of);
        gemm_mfma<2, 2, 0, 1, 0, 0><<<dim3(8, 32), 256, 0, stream>>>(
            of, woT + (size_t)l * 512 * 512, prm + OB_BO + l * 512, xf, xf, nullptr,
            R, DMODEL, DMODEL);
        ln_bf_kernel<<<R, 256, 0, stream>>>(xf, prm + OB_L2G + l * 512, prm + OB_L2B + l * 512, yf);
        gemm_mfma<4, 2, 1, 0, 1, 0><<<dim3(32, 16), 256, 0, stream>>>(
            yf, w1T + (size_t)l * 2048 * 512, prm + OB_B1 + l * 2048, nullptr, hf, nullptr,
            R, DFFN, DMODEL);
        gemm_mfma<2, 2, 0, 1, 0, 0><<<dim3(8, 32), 256, 0, stream>>>(
            hf, w2T + (size_t)l * 512 * 2048, prm + OB_B2 + l * 512, xf, xf, nullptr,
            R, DMODEL, DFFN);
    }
    ln_out_kernel<<<R, 256, 0, stream>>>(xf, prm + OB_FNG, prm + OB_FNB, d_out, flag);
}